// Round 13
// baseline (846.630 us; speedup 1.0000x reference)
//
#include <hip/hip_runtime.h>
#include <hip/hip_bf16.h>

#define HID 1024
#define NH 4
#define HD 256
#define NCH 64
#define BB 4
#define LL 4096
#define ROWS (BB*LL)
#define SSIZE (BB*NH*HD*HD)

typedef __hip_bfloat16 bf16;
typedef __attribute__((ext_vector_type(8))) short short8;
typedef __attribute__((ext_vector_type(4))) float f32x4;

struct u16x4 { unsigned short x, y, z, w; };

__device__ __forceinline__ float bfu2f(unsigned short u) {
  return __uint_as_float(((unsigned int)u) << 16);
}
__device__ __forceinline__ unsigned short f2bfu(float f) {
  unsigned int x = __float_as_uint(f);
  return (unsigned short)((x + 0x7FFFu + ((x >> 16) & 1u)) >> 16);
}
__device__ __forceinline__ float ldv(const float* p) { return *p; }
__device__ __forceinline__ float ldv(const bf16* p) { return bfu2f(*(const unsigned short*)p); }
__device__ __forceinline__ float4 ld4(const float* p) { return *(const float4*)p; }
__device__ __forceinline__ float4 ld4(const bf16* p) {
  u16x4 u = *(const u16x4*)p;
  return make_float4(bfu2f(u.x), bfu2f(u.y), bfu2f(u.z), bfu2f(u.w));
}
__device__ __forceinline__ void st4(float* p, float4 v) { *(float4*)p = v; }
__device__ __forceinline__ void st4(bf16* p, float4 v) {
  u16x4 u; u.x = f2bfu(v.x); u.y = f2bfu(v.y); u.z = f2bfu(v.z); u.w = f2bfu(v.w);
  *(u16x4*)p = u;
}

typedef const __attribute__((address_space(1))) unsigned int* gptr_t;
typedef __attribute__((address_space(3))) unsigned int* lptr_t;
__device__ __forceinline__ void gload16(const void* g, void* l) {
  __builtin_amdgcn_global_load_lds((gptr_t)g, (lptr_t)l, 16, 0, 0);
}

// ---------------- beta = sigmoid(x @ Wb) ----------------
__global__ __launch_bounds__(256)
void beta_kernel(const float* __restrict__ x, const float* __restrict__ Wb,
                 float* __restrict__ beta) {
  const int wave = threadIdx.x >> 6, lane = threadIdx.x & 63;
  const int m = (blockIdx.x << 2) + wave;
  const float* xr = x + (size_t)m * HID;
  float a0 = 0.f, a1 = 0.f, a2 = 0.f, a3 = 0.f;
#pragma unroll
  for (int it = 0; it < 16; ++it) {
    int kk = lane + (it << 6);
    float xv = xr[kk];
    float4 w = *(const float4*)&Wb[kk << 2];
    a0 += xv * w.x; a1 += xv * w.y; a2 += xv * w.z; a3 += xv * w.w;
  }
#pragma unroll
  for (int off = 32; off; off >>= 1) {
    a0 += __shfl_xor(a0, off); a1 += __shfl_xor(a1, off);
    a2 += __shfl_xor(a2, off); a3 += __shfl_xor(a3, off);
  }
  if (lane == 0) {
    float4 r;
    r.x = 1.f / (1.f + expf(-a0)); r.y = 1.f / (1.f + expf(-a1));
    r.z = 1.f / (1.f + expf(-a2)); r.w = 1.f / (1.f + expf(-a3));
    *(float4*)&beta[m << 2] = r;
  }
}

// ---- convert x -> hi (bf16) + lo (bf16 of residual) ----
__global__ __launch_bounds__(256)
void convX2_kernel(const float* __restrict__ x, bf16* __restrict__ hi,
                   bf16* __restrict__ lo) {
  size_t i = ((size_t)blockIdx.x * 256 + threadIdx.x) << 2;
  float4 v = *(const float4*)&x[i];
  u16x4 h; h.x = f2bfu(v.x); h.y = f2bfu(v.y); h.z = f2bfu(v.z); h.w = f2bfu(v.w);
  *(u16x4*)&hi[i] = h;
  u16x4 l;
  l.x = f2bfu(v.x - bfu2f(h.x)); l.y = f2bfu(v.y - bfu2f(h.y));
  l.z = f2bfu(v.z - bfu2f(h.z)); l.w = f2bfu(v.w - bfu2f(h.w));
  *(u16x4*)&lo[i] = l;
}

// ---- convert + transpose weight: Wt[n][k] = bf16(W[k][n]) ----
__global__ __launch_bounds__(256)
void convT_kernel(const float* __restrict__ W, unsigned short* __restrict__ Wt) {
  __shared__ unsigned short t[64][68];
  const int kt = blockIdx.x << 6, nt = blockIdx.y << 6;
  const int tid = threadIdx.x;
#pragma unroll
  for (int i = 0; i < 16; ++i) {
    int idx = tid + (i << 8);
    int r = idx >> 6, c = idx & 63;
    t[r][c] = f2bfu(W[(size_t)(kt + r) * HID + nt + c]);
  }
  __syncthreads();
#pragma unroll
  for (int i = 0; i < 16; ++i) {
    int idx = tid + (i << 8);
    int n = idx >> 6, kk = idx & 63;
    Wt[(size_t)(nt + n) * HID + kt + kk] = t[kk][n];
  }
}

// ---- convert + transpose weight into hi/lo bf16 pair ----
__global__ __launch_bounds__(256)
void convT2_kernel(const float* __restrict__ W, unsigned short* __restrict__ Wht,
                   unsigned short* __restrict__ Wlt) {
  __shared__ float t[64][65];
  const int kt = blockIdx.x << 6, nt = blockIdx.y << 6;
  const int tid = threadIdx.x;
#pragma unroll
  for (int i = 0; i < 16; ++i) {
    int idx = tid + (i << 8);
    int r = idx >> 6, c = idx & 63;
    t[r][c] = W[(size_t)(kt + r) * HID + nt + c];
  }
  __syncthreads();
#pragma unroll
  for (int i = 0; i < 16; ++i) {
    int idx = tid + (i << 8);
    int n = idx >> 6, kk = idx & 63;
    float v = t[kk][n];
    unsigned short h = f2bfu(v);
    Wht[(size_t)(nt + n) * HID + kt + kk] = h;
    Wlt[(size_t)(nt + n) * HID + kt + kk] = f2bfu(v - bfu2f(h));
  }
}

// ---- transpose k: kt[ch][row] = bf16(kbuf[row][ch]) ----
__global__ __launch_bounds__(256)
void ktrans_kernel(const float* __restrict__ k, unsigned short* __restrict__ kt) {
  __shared__ float t[64][65];
  const int r0 = blockIdx.x << 6, c0 = blockIdx.y << 6;
  const int tid = threadIdx.x;
#pragma unroll
  for (int i = 0; i < 16; ++i) {
    int idx = tid + (i << 8);
    int rr = idx >> 6, cc = idx & 63;
    t[rr][cc] = k[(size_t)(r0 + rr) * HID + c0 + cc];
  }
  __syncthreads();
#pragma unroll
  for (int i = 0; i < 16; ++i) {
    int idx = tid + (i << 8);
    int cc = idx >> 6, rr = idx & 63;
    kt[(size_t)(c0 + cc) * ROWS + r0 + rr] = f2bfu(t[rr][cc]);
  }
}

// ---- bf16 MFMA GEMM: C = A @ Bt^T (Bt pre-transposed bf16) ----
__global__ __launch_bounds__(256)
void mfma_gemm(const unsigned short* __restrict__ A,
               const unsigned short* __restrict__ Bt, float* __restrict__ C) {
  __shared__ unsigned short Asl[128 * 32];
  __shared__ unsigned short Bsl[128 * 32];
  const int tid = threadIdx.x;
  const int wave = tid >> 6, lane = tid & 63;
  const int m0 = blockIdx.x << 7, n0 = blockIdx.y << 7;
  const int wr = wave >> 1, wc = wave & 1;
  f32x4 acc[4][4] = {};
  const int cA = (wave << 6) + lane;
  for (int k0 = 0; k0 < HID; k0 += 32) {
#pragma unroll
    for (int i = 0; i < 2; ++i) {
      int c = cA + (i << 8);
      int row = c >> 2, ko = (c & 3) << 3;
      gload16(&A[(size_t)(m0 + row) * HID + k0 + ko],
              &Asl[(size_t)((i << 8) + (wave << 6)) * 8]);
      gload16(&Bt[(size_t)(n0 + row) * HID + k0 + ko],
              &Bsl[(size_t)((i << 8) + (wave << 6)) * 8]);
    }
    __syncthreads();
    short8 af[4], bfr[4];
#pragma unroll
    for (int f = 0; f < 4; ++f) {
      int ra = (wr << 6) + (f << 4) + (lane & 15);
      af[f] = *(const short8*)&Asl[ra * 32 + ((lane >> 4) << 3)];
      int rb = (wc << 6) + (f << 4) + (lane & 15);
      bfr[f] = *(const short8*)&Bsl[rb * 32 + ((lane >> 4) << 3)];
    }
#pragma unroll
    for (int i = 0; i < 4; ++i)
#pragma unroll
      for (int j = 0; j < 4; ++j)
        acc[i][j] = __builtin_amdgcn_mfma_f32_16x16x32_bf16(af[i], bfr[j],
                                                            acc[i][j], 0, 0, 0);
    __syncthreads();
  }
#pragma unroll
  for (int i = 0; i < 4; ++i) {
    int r0 = m0 + (wr << 6) + (i << 4) + ((lane >> 4) << 2);
#pragma unroll
    for (int j = 0; j < 4; ++j) {
      int c0 = n0 + (wc << 6) + (j << 4) + (lane & 15);
#pragma unroll
      for (int r = 0; r < 4; ++r)
        C[(size_t)(r0 + r) * HID + c0] = acc[i][j][r];
    }
  }
}

// ---- split-bf16 MFMA GEMM: C = (Ah+Al) @ (Bh+Bl)^T, dropping Al*Bl ----
__global__ __launch_bounds__(256)
void mfma_gemm3(const unsigned short* __restrict__ Ah_,
                const unsigned short* __restrict__ Al_,
                const unsigned short* __restrict__ Bh_,
                const unsigned short* __restrict__ Bl_,
                float* __restrict__ C) {
  __shared__ unsigned short Ah[128 * 32];
  __shared__ unsigned short Al[128 * 32];
  __shared__ unsigned short Bh[128 * 32];
  __shared__ unsigned short Bl[128 * 32];
  const int tid = threadIdx.x;
  const int wave = tid >> 6, lane = tid & 63;
  const int m0 = blockIdx.x << 7, n0 = blockIdx.y << 7;
  const int wr = wave >> 1, wc = wave & 1;
  f32x4 acc[4][4] = {};
  const int cA = (wave << 6) + lane;
  for (int k0 = 0; k0 < HID; k0 += 32) {
#pragma unroll
    for (int i = 0; i < 2; ++i) {
      int c = cA + (i << 8);
      int row = c >> 2, ko = (c & 3) << 3;
      size_t ga = (size_t)(m0 + row) * HID + k0 + ko;
      size_t gb = (size_t)(n0 + row) * HID + k0 + ko;
      size_t ldst = (size_t)((i << 8) + (wave << 6)) * 8;
      gload16(&Ah_[ga], &Ah[ldst]);
      gload16(&Al_[ga], &Al[ldst]);
      gload16(&Bh_[gb], &Bh[ldst]);
      gload16(&Bl_[gb], &Bl[ldst]);
    }
    __syncthreads();
    short8 ah[4], al[4], bh[4], bl[4];
#pragma unroll
    for (int f = 0; f < 4; ++f) {
      int ra = ((wr << 6) + (f << 4) + (lane & 15)) * 32 + ((lane >> 4) << 3);
      ah[f] = *(const short8*)&Ah[ra];
      al[f] = *(const short8*)&Al[ra];
      int rb = ((wc << 6) + (f << 4) + (lane & 15)) * 32 + ((lane >> 4) << 3);
      bh[f] = *(const short8*)&Bh[rb];
      bl[f] = *(const short8*)&Bl[rb];
    }
#pragma unroll
    for (int i = 0; i < 4; ++i)
#pragma unroll
      for (int j = 0; j < 4; ++j) {
        f32x4 a = acc[i][j];
        a = __builtin_amdgcn_mfma_f32_16x16x32_bf16(al[i], bh[j], a, 0, 0, 0);
        a = __builtin_amdgcn_mfma_f32_16x16x32_bf16(ah[i], bl[j], a, 0, 0, 0);
        a = __builtin_amdgcn_mfma_f32_16x16x32_bf16(ah[i], bh[j], a, 0, 0, 0);
        acc[i][j] = a;
      }
    __syncthreads();
  }
#pragma unroll
  for (int i = 0; i < 4; ++i) {
    int r0 = m0 + (wr << 6) + (i << 4) + ((lane >> 4) << 2);
#pragma unroll
    for (int j = 0; j < 4; ++j) {
      int c0 = n0 + (wc << 6) + (j << 4) + (lane & 15);
#pragma unroll
      for (int r = 0; r < 4; ++r)
        C[(size_t)(r0 + r) * HID + c0] = acc[i][j][r];
    }
  }
}

// ---- MFMA GEMM for S: C[256x256] += A[m][K]·B[n][K] per (bh, K-group) ----
__global__ __launch_bounds__(256)
void mfma_gemmS(const unsigned short* __restrict__ At,
                const unsigned short* __restrict__ Bt,
                float* __restrict__ Spart, int ngroups) {
  __shared__ unsigned short Asl[128 * 32];
  __shared__ unsigned short Bsl[128 * 32];
  const int tid = threadIdx.x;
  const int wave = tid >> 6, lane = tid & 63;
  const int m0 = blockIdx.x << 7, n0 = blockIdx.y << 7;
  const int bh = blockIdx.z / ngroups;
  const int ng = blockIdx.z % ngroups;
  const int b = bh >> 2, h = bh & 3;
  const size_t kbase = (size_t)b * LL + (size_t)ng * (LL / ngroups);
  const int wr = wave >> 1, wc = wave & 1;
  f32x4 acc[4][4] = {};
  const int cA = (wave << 6) + lane;
  for (int k0 = 0; k0 < LL / ngroups; k0 += 32) {
#pragma unroll
    for (int i = 0; i < 2; ++i) {
      int c = cA + (i << 8);
      int row = c >> 2, ko = (c & 3) << 3;
      gload16(&At[((size_t)(h * HD + m0 + row)) * ROWS + kbase + k0 + ko],
              &Asl[(size_t)((i << 8) + (wave << 6)) * 8]);
      gload16(&Bt[((size_t)(bh * HD + n0 + row)) * LL + (size_t)ng * (LL / ngroups) + k0 + ko],
              &Bsl[(size_t)((i << 8) + (wave << 6)) * 8]);
    }
    __syncthreads();
    short8 af[4], bfr[4];
#pragma unroll
    for (int f = 0; f < 4; ++f) {
      int ra = (wr << 6) + (f << 4) + (lane & 15);
      af[f] = *(const short8*)&Asl[ra * 32 + ((lane >> 4) << 3)];
      int rb = (wc << 6) + (f << 4) + (lane & 15);
      bfr[f] = *(const short8*)&Bsl[rb * 32 + ((lane >> 4) << 3)];
    }
#pragma unroll
    for (int i = 0; i < 4; ++i)
#pragma unroll
      for (int j = 0; j < 4; ++j)
        acc[i][j] = __builtin_amdgcn_mfma_f32_16x16x32_bf16(af[i], bfr[j],
                                                            acc[i][j], 0, 0, 0);
    __syncthreads();
  }
  float* Cp = Spart + (size_t)ng * SSIZE + (size_t)bh * HD * HD;
#pragma unroll
  for (int i = 0; i < 4; ++i) {
    int r0 = m0 + (wr << 6) + (i << 4) + ((lane >> 4) << 2);
#pragma unroll
    for (int j = 0; j < 4; ++j) {
      int c0 = n0 + (wc << 6) + (j << 4) + (lane & 15);
#pragma unroll
      for (int r = 0; r < 4; ++r)
        Cp[(size_t)(r0 + r) * HD + c0] = acc[i][j][r];
    }
  }
}

// ------- causal depthwise conv(K=4) + SiLU (+L2 norm / +beta) -------
template <int MODE, typename ST>
__global__ __launch_bounds__(256)
void conv_kernel(const float* __restrict__ lin, const float* __restrict__ w,
                 const float* __restrict__ beta, ST* __restrict__ out) {
  const int row = blockIdx.x;
  const int l = row & (LL - 1);
  const int tid = threadIdx.x;
  const int ch = tid << 2;
  float wv[4][4];
#pragma unroll
  for (int j = 0; j < 4; ++j) {
    float4 t4 = *(const float4*)&w[(ch + j) << 2];
    wv[j][0] = t4.x; wv[j][1] = t4.y; wv[j][2] = t4.z; wv[j][3] = t4.w;
  }
  float y[4] = {0.f, 0.f, 0.f, 0.f};
#pragma unroll
  for (int t = 0; t < 4; ++t) {
    if (l - 3 + t >= 0) {
      float4 xv = *(const float4*)&lin[(size_t)(row - 3 + t) * HID + ch];
      y[0] += xv.x * wv[0][t]; y[1] += xv.y * wv[1][t];
      y[2] += xv.z * wv[2][t]; y[3] += xv.w * wv[3][t];
    }
  }
#pragma unroll
  for (int j = 0; j < 4; ++j) y[j] = y[j] / (1.f + expf(-y[j]));
  float scale;
  if (MODE < 2) {
    float ss = y[0]*y[0] + y[1]*y[1] + y[2]*y[2] + y[3]*y[3];
#pragma unroll
    for (int off = 32; off; off >>= 1) ss += __shfl_xor(ss, off);
    scale = 1.f / sqrtf(ss);
  } else {
    scale = beta[(row << 2) + (tid >> 6)];
  }
  st4(&out[(size_t)row * HID + ch],
      make_float4(y[0]*scale, y[1]*scale, y[2]*scale, y[3]*scale));
}

// ---- per-(b,n): T recurrence (fp32), store T ----
__global__ __launch_bounds__(256)
void chunkT_kernel(const float* __restrict__ k, const float* __restrict__ beta,
                   float* __restrict__ Tg) {
  __shared__ float T[64][68];
  __shared__ float S1[64][68];
  __shared__ float S2[64][68];
  __shared__ float row_s[64];
  const int bn = blockIdx.x;
  const size_t base = (size_t)bn * 64 * HID;
  const int tid = threadIdx.x;
  const int tr = tid >> 4, tc = tid & 15;
  float acc[4][4] = {{0.f}};
  for (int d0 = 0; d0 < HID; d0 += 64) {
    const int h = d0 >> 8;
#pragma unroll
    for (int p = 0; p < 4; ++p) {
      int rr = (tid >> 4) + (p << 4);
      int c4 = (tid & 15) << 2;
      float4 a = *(const float4*)&k[base + (size_t)rr * HID + d0 + c4];
      float bta = beta[(((bn << 6) + rr) << 2) + h];
      S2[c4 + 0][rr] = a.x; S2[c4 + 1][rr] = a.y;
      S2[c4 + 2][rr] = a.z; S2[c4 + 3][rr] = a.w;
      S1[c4 + 0][rr] = a.x * bta; S1[c4 + 1][rr] = a.y * bta;
      S1[c4 + 2][rr] = a.z * bta; S1[c4 + 3][rr] = a.w * bta;
    }
    __syncthreads();
#pragma unroll
    for (int dd = 0; dd < 64; ++dd) {
      float4 a = *(const float4*)&S1[dd][tr << 2];
      float4 b = *(const float4*)&S2[dd][tc << 2];
      acc[0][0] += a.x*b.x; acc[0][1] += a.x*b.y; acc[0][2] += a.x*b.z; acc[0][3] += a.x*b.w;
      acc[1][0] += a.y*b.x; acc[1][1] += a.y*b.y; acc[1][2] += a.y*b.z; acc[1][3] += a.y*b.w;
      acc[2][0] += a.z*b.x; acc[2][1] += a.z*b.y; acc[2][2] += a.z*b.z; acc[2][3] += a.z*b.w;
      acc[3][0] += a.w*b.x; acc[3][1] += a.w*b.y; acc[3][2] += a.w*b.z; acc[3][3] += a.w*b.w;
    }
    __syncthreads();
  }
#pragma unroll
  for (int i = 0; i < 4; ++i)
#pragma unroll
    for (int j = 0; j < 4; ++j) {
      int ri = (tr << 2) + i, cj = (tc << 2) + j;
      T[ri][cj] = (ri == cj) ? 1.f : (ri > cj ? -acc[i][j] : 0.f);
    }
  __syncthreads();
  for (int i = 1; i < 64; ++i) {
    if (tid < 64) row_s[tid] = T[i][tid];
    __syncthreads();
    if (tid < 64) {
      float a = 0.f;
#pragma unroll 8
      for (int j = 0; j < 64; ++j) a += row_s[j] * T[j][tid];
      if (tid < i) T[i][tid] = row_s[tid] + a;
    }
    __syncthreads();
  }
#pragma unroll
  for (int ii = 0; ii < 4; ++ii) {
    int off = (tid << 4) + (ii << 2);
    int c = off >> 6, j = off & 63;
    *(float4*)&Tg[(size_t)bn * 4096 + off] = *(const float4*)&T[c][j];
  }
}

// ---- P,R via ct[j,ch] = sum_c T[c,j]*k[c,ch] ----
template <typename ST>
__global__ __launch_bounds__(256)
void prct_kernel(const float* __restrict__ k, const ST* __restrict__ v,
                 const float* __restrict__ beta, const float* __restrict__ Tg,
                 float* __restrict__ P, float* __restrict__ R) {
  __shared__ float Ts[4096];
  __shared__ float bs[64];
  const int bn = blockIdx.x >> 2, h = blockIdx.x & 3;
  const int tid = threadIdx.x;
#pragma unroll
  for (int ii = 0; ii < 4; ++ii) {
    int off = (tid << 4) + (ii << 2);
    *(float4*)&Ts[off] = *(const float4*)&Tg[(size_t)bn * 4096 + off];
  }
  if (tid < 64) bs[tid] = beta[(((bn << 6) + tid) << 2) + h];
  __syncthreads();
  const int ch = (h << 8) + tid;
  const size_t base = (size_t)bn * 64 * HID;
  float ct[64];
#pragma unroll
  for (int j = 0; j < 64; ++j) ct[j] = 0.f;
  for (int c = 0; c < 64; ++c) {
    float kc = k[base + (size_t)c * HID + ch];
#pragma unroll
    for (int j = 0; j < 64; ++j) ct[j] += Ts[(c << 6) + j] * kc;
  }
  float p = 0.f, r = 0.f;
#pragma unroll
  for (int j = 0; j < 64; ++j) {
    float kj = k[base + (size_t)j * HID + ch];
    float vj = ldv(&v[base + (size_t)j * HID + ch]);
    p += bs[j] * kj * ct[j];
    r += vj * ct[j];
  }
  P[(size_t)bn * HID + ch] = p;
  R[(size_t)bn * HID + ch] = r;
}

// ---- diagonal scan ----
__global__ __launch_bounds__(256)
void scan_kernel(const float* __restrict__ P, const float* __restrict__ R,
                 float* __restrict__ Sdp) {
  const int b = blockIdx.x >> 2;
  const int ch = ((blockIdx.x & 3) << 8) + threadIdx.x;
  float S = 0.f;
  for (int n = 0; n < 64; ++n) {
    Sdp[(size_t)((n << 2) + b) * HID + ch] = S;
    float p = P[(size_t)((b << 6) + n) * HID + ch];
    float r = R[(size_t)((b << 6) + n) * HID + ch];
    S = S * (1.f - p) + r;
  }
}

// ---- Ai ----
template <typename ST>
__global__ __launch_bounds__(256)
void ai_kernel(const ST* __restrict__ q, const float* __restrict__ k,
               float* __restrict__ Ai) {
  const int bn = blockIdx.x;
  const int b = bn >> 6;
  const int wave = threadIdx.x >> 6, lane = threadIdx.x & 63;
  const size_t roff = ((size_t)bn * 64 + wave) * HID;
  float s = 0.f;
#pragma unroll
  for (int it = 0; it < 4; ++it) {
    int d = (lane << 2) + (it << 8);
    float4 a = ld4(&q[roff + d]);
    float4 b4 = *(const float4*)&k[roff + d];
    s += a.x*b4.x + a.y*b4.y + a.z*b4.z + a.w*b4.w;
  }
#pragma unroll
  for (int off = 32; off; off >>= 1) s += __shfl_xor(s, off);
  if (lane == 0) Ai[(bn << 2) + wave] = (wave <= b) ? s : 0.f;
}

// ---- ucompute: u = T@(v - beta*k*Sd) in fp32, write Ut[bh*256+e][row] bf16 ----
__global__ __launch_bounds__(256)
void ucompute_kernel(const float* __restrict__ k, const bf16* __restrict__ v,
                     const float* __restrict__ beta, const float* __restrict__ Tg,
                     const float* __restrict__ Sdp, unsigned short* __restrict__ Ut) {
  __shared__ float Ts[4096];
  __shared__ float va[64][132];
  __shared__ float bs[64];
  const int bn = blockIdx.x >> 3;
  const int rr2 = blockIdx.x & 7;
  const int h = rr2 >> 1, eh = rr2 & 1;
  const int b = bn >> 6, nl = bn & 63;
  const int tid = threadIdx.x;
#pragma unroll
  for (int ii = 0; ii < 4; ++ii) {
    int off = (tid << 4) + (ii << 2);
    *(float4*)&Ts[off] = *(const float4*)&Tg[(size_t)bn * 4096 + off];
  }
  if (tid < 64) bs[tid] = beta[(((bn << 6) + tid) << 2) + h];
  __syncthreads();
  const size_t base = (size_t)bn * 64 * HID;
  const int ch0 = (h << 8) + (eh << 7);
#pragma unroll
  for (int p = 0; p < 8; ++p) {
    int idx = tid + (p << 8);
    int row = idx >> 5;
    int col4 = (idx & 31) << 2;
    int chg = ch0 + col4;
    float4 sd4 = *(const float4*)&Sdp[(size_t)((nl << 2) + b) * HID + chg];
    float4 k4 = *(const float4*)&k[base + (size_t)row * HID + chg];
    float4 v4 = ld4(&v[base + (size_t)row * HID + chg]);
    float bt = bs[row];
    va[row][col4 + 0] = v4.x - bt * k4.x * sd4.x;
    va[row][col4 + 1] = v4.y - bt * k4.y * sd4.y;
    va[row][col4 + 2] = v4.z - bt * k4.z * sd4.z;
    va[row][col4 + 3] = v4.w - bt * k4.w * sd4.w;
  }
  __syncthreads();
  const int e = tid & 127;
  const int chalf = tid >> 7;
  float acc[32];
#pragma unroll
  for (int c2 = 0; c2 < 32; ++c2) acc[c2] = 0.f;
  for (int j = 0; j < 64; ++j) {
    float vaj = va[j][e];
#pragma unroll
    for (int c2 = 0; c2 < 32; ++c2)
      acc[c2] += Ts[((chalf << 5) + c2) * 64 + j] * vaj;
  }
  const size_t ub = ((size_t)(((b << 2) + h) * HD) + (eh << 7) + e) * LL
                  + (nl << 6) + (chalf << 5);
#pragma unroll
  for (int c4 = 0; c4 < 8; ++c4) {
    u16x4 u;
    u.x = f2bfu(acc[(c4 << 2) + 0]); u.y = f2bfu(acc[(c4 << 2) + 1]);
    u.z = f2bfu(acc[(c4 << 2) + 2]); u.w = f2bfu(acc[(c4 << 2) + 3]);
    *(u16x4*)&Ut[ub + (c4 << 2)] = u;
  }
}

// ---- o = q*Sd + (c<=b)*Ai*u(from Ut), RMSNorm*g ; in-place over q ----
template <typename ST>
__global__ __launch_bounds__(256)
void o_kernel(ST* __restrict__ q, const float* __restrict__ Sdp,
              const unsigned short* __restrict__ Ut, const float* __restrict__ Ai,
              const float* __restrict__ g) {
  const int row = blockIdx.x;
  const int b = row >> 12;
  const int l = row & (LL - 1);
  const int n = l >> 6, c = l & 63;
  const int ch = threadIdx.x << 2;
  const size_t ro = (size_t)row * HID;
  float4 qv = ld4(&q[ro + ch]);
  float4 sd = *(const float4*)&Sdp[(size_t)((n << 2) + b) * HID + ch];
  float ox = qv.x*sd.x, oy = qv.y*sd.y, oz = qv.z*sd.z, ow = qv.w*sd.w;
  if (c <= b) {
    int bn = (b << 6) + n;
    float a = Ai[(bn << 2) + c];
    const int h = ch >> 8, e = ch & 255;
    const size_t ub = ((size_t)(((b << 2) + h) * HD) + e) * LL + (n << 6) + c;
    ox += a * bfu2f(Ut[ub + 0 * LL]);
    oy += a * bfu2f(Ut[ub + 1 * LL]);
    oz += a * bfu2f(Ut[ub + 2 * LL]);
    ow += a * bfu2f(Ut[ub + 3 * LL]);
  }
  float ss = ox*ox + oy*oy + oz*oz + ow*ow;
#pragma unroll
  for (int off = 32; off; off >>= 1) ss += __shfl_xor(ss, off);
  float scale = 1.f / sqrtf(ss * (1.f / HD) + 1e-5f);
  float4 gv = *(const float4*)&g[ch & (HD - 1)];
  st4(&q[ro + ch], make_float4(ox*scale*gv.x, oy*scale*gv.y, oz*scale*gv.z, ow*scale*gv.w));
}

// ---- reduce partials -> Sout ----
__global__ __launch_bounds__(256)
void sreduce_kernel(const float* __restrict__ Spart, float* __restrict__ Sout,
                    int ngroups) {
  size_t i = ((size_t)blockIdx.x * 256 + threadIdx.x) << 2;
  float4 s = make_float4(0.f, 0.f, 0.f, 0.f);
  for (int g = 0; g < ngroups; ++g) {
    float4 p = *(const float4*)&Spart[(size_t)g * SSIZE + i];
    s.x += p.x; s.y += p.y; s.z += p.z; s.w += p.w;
  }
  *(float4*)&Sout[i] = s;
}

extern "C" void kernel_launch(void* const* d_in, const int* in_sizes, int n_in,
                              void* d_out, int out_size, void* d_ws, size_t ws_size,
                              hipStream_t stream) {
  const float* x  = (const float*)d_in[0];
  const float* Wq = (const float*)d_in[1];
  const float* Wk = (const float*)d_in[2];
  const float* Wv = (const float*)d_in[3];
  const float* Wb = (const float*)d_in[4];
  const float* cq = (const float*)d_in[5];
  const float* ck = (const float*)d_in[6];
  const float* cv = (const float*)d_in[7];
  const float* g  = (const float*)d_in[8];
  const float* Wo = (const float*)d_in[9];
  float* out  = (float*)d_out;
  float* Sout = out + (size_t)ROWS * HID;

  const size_t F = (size_t)ROWS * HID;
  char* w = (char*)d_ws;
  float* kbuf  = (float*)w;  w += F * 4;   // -> Spart after ucompute
  bf16*  xb    = (bf16*)w;   w += F * 2;   // -> kt after v-GEMM
  bf16*  qbuf  = (bf16*)w;   w += F * 2;   // xlo first, then q
  bf16*  vbuf  = (bf16*)w;   w += F * 2;
  unsigned short* Wqt  = (unsigned short*)w; w += (size_t)HID * HID * 2;
  unsigned short* Wvt  = (unsigned short*)w; w += (size_t)HID * HID * 2;
  unsigned short* Wot  = (unsigned short*)w; w += (size_t)HID * HID * 2;
  unsigned short* Wkht = (unsigned short*)w; w += (size_t)HID * HID * 2;
  unsigned short* Wklt = (unsigned short*)w; w += (size_t)HID * HID * 2;
  float* Tg    = (float*)w;  w += (size_t)BB * NCH * 4096 * 4;
  float* betab = (float*)w;  w += (size_t)ROWS * NH * 4;
  float* Aib   = (float*)w;  w += (size_t)BB * NCH * 4 * 4;
  float* Pb    = (float*)w;  w += (size_t)BB * NCH * HID * 4;
  float* Rb    = (float*)w;  w += (size_t)BB * NCH * HID * 4;
  float* Sdp   = (float*)w;  w += (size_t)BB * NCH * HID * 4;
  const size_t need = (size_t)(w - (char*)d_ws);
  if (ws_size < need) return;

  dim3 gg(ROWS / 128, HID / 128);
  dim3 gt(16, 16);
  float* lin = out;       // d_out[0..16M) scratch; later holds Ut, finally out
  bf16* xlo = qbuf;       // alias: dead once conv<0> writes qbuf

  convX2_kernel<<<F / 1024, 256, 0, stream>>>(x, xb, xlo);
  convT2_kernel<<<gt, 256, 0, stream>>>(Wk, Wkht, Wklt);
  convT_kernel<<<gt, 256, 0, stream>>>(Wq, Wqt);
  convT_kernel<<<gt, 256, 0, stream>>>(Wv, Wvt);
  convT_kernel<<<gt, 256, 0, stream>>>(Wo, Wot);
  beta_kernel<<<ROWS / 4, 256, 0, stream>>>(x, Wb, betab);

  // k first (uses xlo which aliases qbuf)
  mfma_gemm3<<<gg, 256, 0, stream>>>((const unsigned short*)xb,
                                     (const unsigned short*)xlo, Wkht, Wklt, lin);
  conv_kernel<1, float><<<ROWS, 256, 0, stream>>>(lin, ck, betab, kbuf);
  mfma_gemm<<<gg, 256, 0, stream>>>((const unsigned short*)xb, Wqt, lin);
  conv_kernel<0, bf16><<<ROWS, 256, 0, stream>>>(lin, cq, betab, qbuf);
  mfma_gemm<<<gg, 256, 0, stream>>>((const unsigned short*)xb, Wvt, lin);
  conv_kernel<2, bf16><<<ROWS, 256, 0, stream>>>(lin, cv, betab, vbuf);
  // lin (d_out[0..16M)) now free until out-GEMM

  // xb now dead -> kt[ch][row] bf16
  unsigned short* kt = (unsigned short*)xb;
  ktrans_kernel<<<dim3(ROWS / 64, HID / 64), 256, 0, stream>>>(kbuf, kt);

  chunkT_kernel<<<BB * NCH, 256, 0, stream>>>(kbuf, betab, Tg);
  prct_kernel<bf16><<<BB * NCH * NH, 256, 0, stream>>>(kbuf, vbuf, betab, Tg, Pb, Rb);
  scan_kernel<<<16, 256, 0, stream>>>(Pb, Rb, Sdp);
  ai_kernel<bf16><<<BB * NCH, 256, 0, stream>>>(qbuf, kbuf, Aib);

  // Ut (bf16, 32MB) lives in the free d_out scratch region
  unsigned short* Ut = (unsigned short*)lin;
  ucompute_kernel<<<BB * NCH * NH * 2, 256, 0, stream>>>(kbuf, vbuf, betab, Tg,
                                                         Sdp, Ut);
  o_kernel<bf16><<<ROWS, 256, 0, stream>>>(qbuf, Sdp, Ut, Aib, g);

  // kbuf now dead -> Spart (8 x 4MB fp32)
  float* Spart = kbuf;
  const int ngroups = 8;
  mfma_gemmS<<<dim3(2, 2, 16 * ngroups), 256, 0, stream>>>(kt, Ut, Spart, ngroups);
  sreduce_kernel<<<SSIZE / 1024, 256, 0, stream>>>(Spart, Sout, ngroups);

  // final output GEMM overwrites the Ut scratch region with out
  mfma_gemm<<<gg, 256, 0, stream>>>((const unsigned short*)qbuf, Wot, out);
}

// Round 14
// 705.996 us; speedup vs baseline: 1.1992x; 1.1992x over previous
//
#include <hip/hip_runtime.h>
#include <hip/hip_bf16.h>

#define HID 1024
#define NH 4
#define HD 256
#define NCH 64
#define BB 4
#define LL 4096
#define ROWS (BB*LL)
#define SSIZE (BB*NH*HD*HD)

typedef __hip_bfloat16 bf16;
typedef __attribute__((ext_vector_type(8))) short short8;
typedef __attribute__((ext_vector_type(4))) float f32x4;

struct u16x4 { unsigned short x, y, z, w; };

__device__ __forceinline__ float bfu2f(unsigned short u) {
  return __uint_as_float(((unsigned int)u) << 16);
}
__device__ __forceinline__ unsigned short f2bfu(float f) {
  unsigned int x = __float_as_uint(f);
  return (unsigned short)((x + 0x7FFFu + ((x >> 16) & 1u)) >> 16);
}
__device__ __forceinline__ float ldv(const float* p) { return *p; }
__device__ __forceinline__ float ldv(const bf16* p) { return bfu2f(*(const unsigned short*)p); }
__device__ __forceinline__ float4 ld4(const float* p) { return *(const float4*)p; }
__device__ __forceinline__ float4 ld4(const bf16* p) {
  u16x4 u = *(const u16x4*)p;
  return make_float4(bfu2f(u.x), bfu2f(u.y), bfu2f(u.z), bfu2f(u.w));
}
__device__ __forceinline__ void st4(float* p, float4 v) { *(float4*)p = v; }
__device__ __forceinline__ void st4(bf16* p, float4 v) {
  u16x4 u; u.x = f2bfu(v.x); u.y = f2bfu(v.y); u.z = f2bfu(v.z); u.w = f2bfu(v.w);
  *(u16x4*)p = u;
}
__device__ __forceinline__ void stc(float* C, size_t i, float v) { C[i] = v; }
__device__ __forceinline__ void stc(bf16* C, size_t i, float v) {
  ((unsigned short*)C)[i] = f2bfu(v);
}

typedef const __attribute__((address_space(1))) unsigned int* gptr_t;
typedef __attribute__((address_space(3))) unsigned int* lptr_t;
__device__ __forceinline__ void gload16(const void* g, void* l) {
  __builtin_amdgcn_global_load_lds((gptr_t)g, (lptr_t)l, 16, 0, 0);
}

// ---- prep: x -> xb(hi)/xlo(lo) bf16 AND beta = sigmoid(x@Wb), one x pass ----
__global__ __launch_bounds__(256)
void prep_kernel(const float* __restrict__ x, const float* __restrict__ Wb,
                 bf16* __restrict__ hi, bf16* __restrict__ lo,
                 float* __restrict__ beta) {
  const int wave = threadIdx.x >> 6, lane = threadIdx.x & 63;
  const int m = (blockIdx.x << 2) + wave;
  float a0 = 0.f, a1 = 0.f, a2 = 0.f, a3 = 0.f;
#pragma unroll
  for (int it = 0; it < 4; ++it) {
    int f4 = (it << 6) + lane;                 // float4 index 0..255
    size_t e = (size_t)m * 256 + f4;
    float4 v = *(const float4*)&x[e << 2];
    u16x4 h; h.x = f2bfu(v.x); h.y = f2bfu(v.y); h.z = f2bfu(v.z); h.w = f2bfu(v.w);
    *(u16x4*)&hi[e << 2] = h;
    u16x4 l;
    l.x = f2bfu(v.x - bfu2f(h.x)); l.y = f2bfu(v.y - bfu2f(h.y));
    l.z = f2bfu(v.z - bfu2f(h.z)); l.w = f2bfu(v.w - bfu2f(h.w));
    *(u16x4*)&lo[e << 2] = l;
    const float xs[4] = {v.x, v.y, v.z, v.w};
#pragma unroll
    for (int j = 0; j < 4; ++j) {
      float4 wb = *(const float4*)&Wb[((f4 << 2) + j) << 2];
      a0 += xs[j] * wb.x; a1 += xs[j] * wb.y;
      a2 += xs[j] * wb.z; a3 += xs[j] * wb.w;
    }
  }
#pragma unroll
  for (int off = 32; off; off >>= 1) {
    a0 += __shfl_xor(a0, off); a1 += __shfl_xor(a1, off);
    a2 += __shfl_xor(a2, off); a3 += __shfl_xor(a3, off);
  }
  if (lane == 0) {
    float4 r;
    r.x = 1.f / (1.f + expf(-a0)); r.y = 1.f / (1.f + expf(-a1));
    r.z = 1.f / (1.f + expf(-a2)); r.w = 1.f / (1.f + expf(-a3));
    *(float4*)&beta[m << 2] = r;
  }
}

// ---- all weight conversions in one launch: z=0 Wq, z=1 Wv, z=2 Wo, z=3 Wk(hi/lo) ----
__global__ __launch_bounds__(256)
void convT_all(const float* __restrict__ Wq, const float* __restrict__ Wv,
               const float* __restrict__ Wo, const float* __restrict__ Wk,
               unsigned short* __restrict__ Wqt, unsigned short* __restrict__ Wvt,
               unsigned short* __restrict__ Wot, unsigned short* __restrict__ Wkht,
               unsigned short* __restrict__ Wklt) {
  __shared__ float t[64][65];
  const int z = blockIdx.z;
  const float* W = z == 0 ? Wq : z == 1 ? Wv : z == 2 ? Wo : Wk;
  const int kt = blockIdx.x << 6, nt = blockIdx.y << 6;
  const int tid = threadIdx.x;
#pragma unroll
  for (int i = 0; i < 16; ++i) {
    int idx = tid + (i << 8);
    int r = idx >> 6, c = idx & 63;
    t[r][c] = W[(size_t)(kt + r) * HID + nt + c];
  }
  __syncthreads();
  if (z < 3) {
    unsigned short* Wt = z == 0 ? Wqt : z == 1 ? Wvt : Wot;
#pragma unroll
    for (int i = 0; i < 16; ++i) {
      int idx = tid + (i << 8);
      int n = idx >> 6, kk = idx & 63;
      Wt[(size_t)(nt + n) * HID + kt + kk] = f2bfu(t[kk][n]);
    }
  } else {
#pragma unroll
    for (int i = 0; i < 16; ++i) {
      int idx = tid + (i << 8);
      int n = idx >> 6, kk = idx & 63;
      float v = t[kk][n];
      unsigned short h = f2bfu(v);
      Wkht[(size_t)(nt + n) * HID + kt + kk] = h;
      Wklt[(size_t)(nt + n) * HID + kt + kk] = f2bfu(v - bfu2f(h));
    }
  }
}

// ---- transpose k: kt[ch][row] = bf16(kbuf[row][ch]) ----
__global__ __launch_bounds__(256)
void ktrans_kernel(const float* __restrict__ k, unsigned short* __restrict__ kt) {
  __shared__ float t[64][65];
  const int r0 = blockIdx.x << 6, c0 = blockIdx.y << 6;
  const int tid = threadIdx.x;
#pragma unroll
  for (int i = 0; i < 16; ++i) {
    int idx = tid + (i << 8);
    int rr = idx >> 6, cc = idx & 63;
    t[rr][cc] = k[(size_t)(r0 + rr) * HID + c0 + cc];
  }
  __syncthreads();
#pragma unroll
  for (int i = 0; i < 16; ++i) {
    int idx = tid + (i << 8);
    int cc = idx >> 6, rr = idx & 63;
    kt[(size_t)(c0 + cc) * ROWS + r0 + rr] = f2bfu(t[rr][cc]);
  }
}

// ---- bf16 MFMA GEMM: C = A @ Bt^T, output type templated ----
template <typename OT>
__global__ __launch_bounds__(256)
void mfma_gemm(const unsigned short* __restrict__ A,
               const unsigned short* __restrict__ Bt, OT* __restrict__ C) {
  __shared__ unsigned short Asl[128 * 32];
  __shared__ unsigned short Bsl[128 * 32];
  const int tid = threadIdx.x;
  const int wave = tid >> 6, lane = tid & 63;
  const int m0 = blockIdx.x << 7, n0 = blockIdx.y << 7;
  const int wr = wave >> 1, wc = wave & 1;
  f32x4 acc[4][4] = {};
  const int cA = (wave << 6) + lane;
  for (int k0 = 0; k0 < HID; k0 += 32) {
#pragma unroll
    for (int i = 0; i < 2; ++i) {
      int c = cA + (i << 8);
      int row = c >> 2, ko = (c & 3) << 3;
      gload16(&A[(size_t)(m0 + row) * HID + k0 + ko],
              &Asl[(size_t)((i << 8) + (wave << 6)) * 8]);
      gload16(&Bt[(size_t)(n0 + row) * HID + k0 + ko],
              &Bsl[(size_t)((i << 8) + (wave << 6)) * 8]);
    }
    __syncthreads();
    short8 af[4], bfr[4];
#pragma unroll
    for (int f = 0; f < 4; ++f) {
      int ra = (wr << 6) + (f << 4) + (lane & 15);
      af[f] = *(const short8*)&Asl[ra * 32 + ((lane >> 4) << 3)];
      int rb = (wc << 6) + (f << 4) + (lane & 15);
      bfr[f] = *(const short8*)&Bsl[rb * 32 + ((lane >> 4) << 3)];
    }
#pragma unroll
    for (int i = 0; i < 4; ++i)
#pragma unroll
      for (int j = 0; j < 4; ++j)
        acc[i][j] = __builtin_amdgcn_mfma_f32_16x16x32_bf16(af[i], bfr[j],
                                                            acc[i][j], 0, 0, 0);
    __syncthreads();
  }
#pragma unroll
  for (int i = 0; i < 4; ++i) {
    int r0 = m0 + (wr << 6) + (i << 4) + ((lane >> 4) << 2);
#pragma unroll
    for (int j = 0; j < 4; ++j) {
      int c0 = n0 + (wc << 6) + (j << 4) + (lane & 15);
#pragma unroll
      for (int r = 0; r < 4; ++r)
        stc(C, (size_t)(r0 + r) * HID + c0, acc[i][j][r]);
    }
  }
}

// ---- split-bf16 MFMA GEMM: C = (Ah+Al) @ (Bh+Bl)^T, dropping Al*Bl ----
__global__ __launch_bounds__(256)
void mfma_gemm3(const unsigned short* __restrict__ Ah_,
                const unsigned short* __restrict__ Al_,
                const unsigned short* __restrict__ Bh_,
                const unsigned short* __restrict__ Bl_,
                float* __restrict__ C) {
  __shared__ unsigned short Ah[128 * 32];
  __shared__ unsigned short Al[128 * 32];
  __shared__ unsigned short Bh[128 * 32];
  __shared__ unsigned short Bl[128 * 32];
  const int tid = threadIdx.x;
  const int wave = tid >> 6, lane = tid & 63;
  const int m0 = blockIdx.x << 7, n0 = blockIdx.y << 7;
  const int wr = wave >> 1, wc = wave & 1;
  f32x4 acc[4][4] = {};
  const int cA = (wave << 6) + lane;
  for (int k0 = 0; k0 < HID; k0 += 32) {
#pragma unroll
    for (int i = 0; i < 2; ++i) {
      int c = cA + (i << 8);
      int row = c >> 2, ko = (c & 3) << 3;
      size_t ga = (size_t)(m0 + row) * HID + k0 + ko;
      size_t gb = (size_t)(n0 + row) * HID + k0 + ko;
      size_t ldst = (size_t)((i << 8) + (wave << 6)) * 8;
      gload16(&Ah_[ga], &Ah[ldst]);
      gload16(&Al_[ga], &Al[ldst]);
      gload16(&Bh_[gb], &Bh[ldst]);
      gload16(&Bl_[gb], &Bl[ldst]);
    }
    __syncthreads();
    short8 ah[4], al[4], bh[4], bl[4];
#pragma unroll
    for (int f = 0; f < 4; ++f) {
      int ra = ((wr << 6) + (f << 4) + (lane & 15)) * 32 + ((lane >> 4) << 3);
      ah[f] = *(const short8*)&Ah[ra];
      al[f] = *(const short8*)&Al[ra];
      int rb = ((wc << 6) + (f << 4) + (lane & 15)) * 32 + ((lane >> 4) << 3);
      bh[f] = *(const short8*)&Bh[rb];
      bl[f] = *(const short8*)&Bl[rb];
    }
#pragma unroll
    for (int i = 0; i < 4; ++i)
#pragma unroll
      for (int j = 0; j < 4; ++j) {
        f32x4 a = acc[i][j];
        a = __builtin_amdgcn_mfma_f32_16x16x32_bf16(al[i], bh[j], a, 0, 0, 0);
        a = __builtin_amdgcn_mfma_f32_16x16x32_bf16(ah[i], bl[j], a, 0, 0, 0);
        a = __builtin_amdgcn_mfma_f32_16x16x32_bf16(ah[i], bh[j], a, 0, 0, 0);
        acc[i][j] = a;
      }
    __syncthreads();
  }
#pragma unroll
  for (int i = 0; i < 4; ++i) {
    int r0 = m0 + (wr << 6) + (i << 4) + ((lane >> 4) << 2);
#pragma unroll
    for (int j = 0; j < 4; ++j) {
      int c0 = n0 + (wc << 6) + (j << 4) + (lane & 15);
#pragma unroll
      for (int r = 0; r < 4; ++r)
        C[(size_t)(r0 + r) * HID + c0] = acc[i][j][r];
    }
  }
}

// ---- MFMA GEMM for S ----
__global__ __launch_bounds__(256)
void mfma_gemmS(const unsigned short* __restrict__ At,
                const unsigned short* __restrict__ Bt,
                float* __restrict__ Spart, int ngroups) {
  __shared__ unsigned short Asl[128 * 32];
  __shared__ unsigned short Bsl[128 * 32];
  const int tid = threadIdx.x;
  const int wave = tid >> 6, lane = tid & 63;
  const int m0 = blockIdx.x << 7, n0 = blockIdx.y << 7;
  const int bh = blockIdx.z / ngroups;
  const int ng = blockIdx.z % ngroups;
  const int b = bh >> 2, h = bh & 3;
  const size_t kbase = (size_t)b * LL + (size_t)ng * (LL / ngroups);
  const int wr = wave >> 1, wc = wave & 1;
  f32x4 acc[4][4] = {};
  const int cA = (wave << 6) + lane;
  for (int k0 = 0; k0 < LL / ngroups; k0 += 32) {
#pragma unroll
    for (int i = 0; i < 2; ++i) {
      int c = cA + (i << 8);
      int row = c >> 2, ko = (c & 3) << 3;
      gload16(&At[((size_t)(h * HD + m0 + row)) * ROWS + kbase + k0 + ko],
              &Asl[(size_t)((i << 8) + (wave << 6)) * 8]);
      gload16(&Bt[((size_t)(bh * HD + n0 + row)) * LL + (size_t)ng * (LL / ngroups) + k0 + ko],
              &Bsl[(size_t)((i << 8) + (wave << 6)) * 8]);
    }
    __syncthreads();
    short8 af[4], bfr[4];
#pragma unroll
    for (int f = 0; f < 4; ++f) {
      int ra = (wr << 6) + (f << 4) + (lane & 15);
      af[f] = *(const short8*)&Asl[ra * 32 + ((lane >> 4) << 3)];
      int rb = (wc << 6) + (f << 4) + (lane & 15);
      bfr[f] = *(const short8*)&Bsl[rb * 32 + ((lane >> 4) << 3)];
    }
#pragma unroll
    for (int i = 0; i < 4; ++i)
#pragma unroll
      for (int j = 0; j < 4; ++j)
        acc[i][j] = __builtin_amdgcn_mfma_f32_16x16x32_bf16(af[i], bfr[j],
                                                            acc[i][j], 0, 0, 0);
    __syncthreads();
  }
  float* Cp = Spart + (size_t)ng * SSIZE + (size_t)bh * HD * HD;
#pragma unroll
  for (int i = 0; i < 4; ++i) {
    int r0 = m0 + (wr << 6) + (i << 4) + ((lane >> 4) << 2);
#pragma unroll
    for (int j = 0; j < 4; ++j) {
      int c0 = n0 + (wc << 6) + (j << 4) + (lane & 15);
#pragma unroll
      for (int r = 0; r < 4; ++r)
        Cp[(size_t)(r0 + r) * HD + c0] = acc[i][j][r];
    }
  }
}

// ------- conv8: causal depthwise conv(K=4)+SiLU (+norm/+beta), 8 rows/block -------
template <int MODE, typename IT, typename ST>
__global__ __launch_bounds__(256)
void conv8_kernel(const IT* __restrict__ lin, const float* __restrict__ w,
                  const float* __restrict__ beta, ST* __restrict__ out) {
  const int row0 = blockIdx.x << 3;
  const int tid = threadIdx.x;
  const int ch = tid << 2;
  const int h = tid >> 6;
  float wv[4][4];
#pragma unroll
  for (int j = 0; j < 4; ++j) {
    float4 t4 = *(const float4*)&w[(ch + j) << 2];
    wv[j][0] = t4.x; wv[j][1] = t4.y; wv[j][2] = t4.z; wv[j][3] = t4.w;
  }
  const int l0 = row0 & (LL - 1);
  const bool hasprev = (l0 != 0);
  float4 xw0, xw1, xw2, xw3;
  const float4 z4 = make_float4(0.f, 0.f, 0.f, 0.f);
  xw0 = hasprev ? ld4(&lin[(size_t)(row0 - 3) * HID + ch]) : z4;
  xw1 = hasprev ? ld4(&lin[(size_t)(row0 - 2) * HID + ch]) : z4;
  xw2 = hasprev ? ld4(&lin[(size_t)(row0 - 1) * HID + ch]) : z4;
#pragma unroll
  for (int r = 0; r < 8; ++r) {
    const int gr = row0 + r;
    xw3 = ld4(&lin[(size_t)gr * HID + ch]);
    float y[4];
#pragma unroll
    for (int j = 0; j < 4; ++j) {
      float xv0 = j == 0 ? xw0.x : j == 1 ? xw0.y : j == 2 ? xw0.z : xw0.w;
      float xv1 = j == 0 ? xw1.x : j == 1 ? xw1.y : j == 2 ? xw1.z : xw1.w;
      float xv2 = j == 0 ? xw2.x : j == 1 ? xw2.y : j == 2 ? xw2.z : xw2.w;
      float xv3 = j == 0 ? xw3.x : j == 1 ? xw3.y : j == 2 ? xw3.z : xw3.w;
      y[j] = xv0 * wv[j][0] + xv1 * wv[j][1] + xv2 * wv[j][2] + xv3 * wv[j][3];
      y[j] = y[j] / (1.f + expf(-y[j]));
    }
    float scale;
    if (MODE < 2) {
      float ss = y[0]*y[0] + y[1]*y[1] + y[2]*y[2] + y[3]*y[3];
#pragma unroll
      for (int off = 32; off; off >>= 1) ss += __shfl_xor(ss, off);  // wave = head
      scale = 1.f / sqrtf(ss);
    } else {
      scale = beta[(gr << 2) + h];
    }
    st4(&out[(size_t)gr * HID + ch],
        make_float4(y[0]*scale, y[1]*scale, y[2]*scale, y[3]*scale));
    xw0 = xw1; xw1 = xw2; xw2 = xw3;
  }
}

// ---- per-(b,n): T recurrence (fp32), store T ----
__global__ __launch_bounds__(256)
void chunkT_kernel(const float* __restrict__ k, const float* __restrict__ beta,
                   float* __restrict__ Tg) {
  __shared__ float T[64][68];
  __shared__ float S1[64][68];
  __shared__ float S2[64][68];
  __shared__ float row_s[64];
  const int bn = blockIdx.x;
  const size_t base = (size_t)bn * 64 * HID;
  const int tid = threadIdx.x;
  const int tr = tid >> 4, tc = tid & 15;
  float acc[4][4] = {{0.f}};
  for (int d0 = 0; d0 < HID; d0 += 64) {
    const int h = d0 >> 8;
#pragma unroll
    for (int p = 0; p < 4; ++p) {
      int rr = (tid >> 4) + (p << 4);
      int c4 = (tid & 15) << 2;
      float4 a = *(const float4*)&k[base + (size_t)rr * HID + d0 + c4];
      float bta = beta[(((bn << 6) + rr) << 2) + h];
      S2[c4 + 0][rr] = a.x; S2[c4 + 1][rr] = a.y;
      S2[c4 + 2][rr] = a.z; S2[c4 + 3][rr] = a.w;
      S1[c4 + 0][rr] = a.x * bta; S1[c4 + 1][rr] = a.y * bta;
      S1[c4 + 2][rr] = a.z * bta; S1[c4 + 3][rr] = a.w * bta;
    }
    __syncthreads();
#pragma unroll
    for (int dd = 0; dd < 64; ++dd) {
      float4 a = *(const float4*)&S1[dd][tr << 2];
      float4 b = *(const float4*)&S2[dd][tc << 2];
      acc[0][0] += a.x*b.x; acc[0][1] += a.x*b.y; acc[0][2] += a.x*b.z; acc[0][3] += a.x*b.w;
      acc[1][0] += a.y*b.x; acc[1][1] += a.y*b.y; acc[1][2] += a.y*b.z; acc[1][3] += a.y*b.w;
      acc[2][0] += a.z*b.x; acc[2][1] += a.z*b.y; acc[2][2] += a.z*b.z; acc[2][3] += a.z*b.w;
      acc[3][0] += a.w*b.x; acc[3][1] += a.w*b.y; acc[3][2] += a.w*b.z; acc[3][3] += a.w*b.w;
    }
    __syncthreads();
  }
#pragma unroll
  for (int i = 0; i < 4; ++i)
#pragma unroll
    for (int j = 0; j < 4; ++j) {
      int ri = (tr << 2) + i, cj = (tc << 2) + j;
      T[ri][cj] = (ri == cj) ? 1.f : (ri > cj ? -acc[i][j] : 0.f);
    }
  __syncthreads();
  for (int i = 1; i < 64; ++i) {
    if (tid < 64) row_s[tid] = T[i][tid];
    __syncthreads();
    if (tid < 64) {
      float a = 0.f;
#pragma unroll 8
      for (int j = 0; j < 64; ++j) a += row_s[j] * T[j][tid];
      if (tid < i) T[i][tid] = row_s[tid] + a;
    }
    __syncthreads();
  }
#pragma unroll
  for (int ii = 0; ii < 4; ++ii) {
    int off = (tid << 4) + (ii << 2);
    int c = off >> 6, j = off & 63;
    *(float4*)&Tg[(size_t)bn * 4096 + off] = *(const float4*)&T[c][j];
  }
}

// ---- P,R via ct[j,ch] = sum_c T[c,j]*k[c,ch] ----
template <typename ST>
__global__ __launch_bounds__(256)
void prct_kernel(const float* __restrict__ k, const ST* __restrict__ v,
                 const float* __restrict__ beta, const float* __restrict__ Tg,
                 float* __restrict__ P, float* __restrict__ R) {
  __shared__ float Ts[4096];
  __shared__ float bs[64];
  const int bn = blockIdx.x >> 2, h = blockIdx.x & 3;
  const int tid = threadIdx.x;
#pragma unroll
  for (int ii = 0; ii < 4; ++ii) {
    int off = (tid << 4) + (ii << 2);
    *(float4*)&Ts[off] = *(const float4*)&Tg[(size_t)bn * 4096 + off];
  }
  if (tid < 64) bs[tid] = beta[(((bn << 6) + tid) << 2) + h];
  __syncthreads();
  const int ch = (h << 8) + tid;
  const size_t base = (size_t)bn * 64 * HID;
  float ct[64];
#pragma unroll
  for (int j = 0; j < 64; ++j) ct[j] = 0.f;
  for (int c = 0; c < 64; ++c) {
    float kc = k[base + (size_t)c * HID + ch];
#pragma unroll
    for (int j = 0; j < 64; ++j) ct[j] += Ts[(c << 6) + j] * kc;
  }
  float p = 0.f, r = 0.f;
#pragma unroll
  for (int j = 0; j < 64; ++j) {
    float kj = k[base + (size_t)j * HID + ch];
    float vj = ldv(&v[base + (size_t)j * HID + ch]);
    p += bs[j] * kj * ct[j];
    r += vj * ct[j];
  }
  P[(size_t)bn * HID + ch] = p;
  R[(size_t)bn * HID + ch] = r;
}

// ---- diagonal scan ----
__global__ __launch_bounds__(256)
void scan_kernel(const float* __restrict__ P, const float* __restrict__ R,
                 float* __restrict__ Sdp) {
  const int b = blockIdx.x >> 2;
  const int ch = ((blockIdx.x & 3) << 8) + threadIdx.x;
  float S = 0.f;
  for (int n = 0; n < 64; ++n) {
    Sdp[(size_t)((n << 2) + b) * HID + ch] = S;
    float p = P[(size_t)((b << 6) + n) * HID + ch];
    float r = R[(size_t)((b << 6) + n) * HID + ch];
    S = S * (1.f - p) + r;
  }
}

// ---- Ai ----
template <typename ST>
__global__ __launch_bounds__(256)
void ai_kernel(const ST* __restrict__ q, const float* __restrict__ k,
               float* __restrict__ Ai) {
  const int bn = blockIdx.x;
  const int b = bn >> 6;
  const int wave = threadIdx.x >> 6, lane = threadIdx.x & 63;
  const size_t roff = ((size_t)bn * 64 + wave) * HID;
  float s = 0.f;
#pragma unroll
  for (int it = 0; it < 4; ++it) {
    int d = (lane << 2) + (it << 8);
    float4 a = ld4(&q[roff + d]);
    float4 b4 = *(const float4*)&k[roff + d];
    s += a.x*b4.x + a.y*b4.y + a.z*b4.z + a.w*b4.w;
  }
#pragma unroll
  for (int off = 32; off; off >>= 1) s += __shfl_xor(s, off);
  if (lane == 0) Ai[(bn << 2) + wave] = (wave <= b) ? s : 0.f;
}

// ---- ucompute: u = T@(v - beta*k*Sd) in fp32, write Ut[bh*256+e][row] bf16 ----
__global__ __launch_bounds__(256)
void ucompute_kernel(const float* __restrict__ k, const bf16* __restrict__ v,
                     const float* __restrict__ beta, const float* __restrict__ Tg,
                     const float* __restrict__ Sdp, unsigned short* __restrict__ Ut) {
  __shared__ float Ts[4096];
  __shared__ float va[64][132];
  __shared__ float bs[64];
  const int bn = blockIdx.x >> 3;
  const int rr2 = blockIdx.x & 7;
  const int h = rr2 >> 1, eh = rr2 & 1;
  const int b = bn >> 6, nl = bn & 63;
  const int tid = threadIdx.x;
#pragma unroll
  for (int ii = 0; ii < 4; ++ii) {
    int off = (tid << 4) + (ii << 2);
    *(float4*)&Ts[off] = *(const float4*)&Tg[(size_t)bn * 4096 + off];
  }
  if (tid < 64) bs[tid] = beta[(((bn << 6) + tid) << 2) + h];
  __syncthreads();
  const size_t base = (size_t)bn * 64 * HID;
  const int ch0 = (h << 8) + (eh << 7);
#pragma unroll
  for (int p = 0; p < 8; ++p) {
    int idx = tid + (p << 8);
    int row = idx >> 5;
    int col4 = (idx & 31) << 2;
    int chg = ch0 + col4;
    float4 sd4 = *(const float4*)&Sdp[(size_t)((nl << 2) + b) * HID + chg];
    float4 k4 = *(const float4*)&k[base + (size_t)row * HID + chg];
    float4 v4 = ld4(&v[base + (size_t)row * HID + chg]);
    float bt = bs[row];
    va[row][col4 + 0] = v4.x - bt * k4.x * sd4.x;
    va[row][col4 + 1] = v4.y - bt * k4.y * sd4.y;
    va[row][col4 + 2] = v4.z - bt * k4.z * sd4.z;
    va[row][col4 + 3] = v4.w - bt * k4.w * sd4.w;
  }
  __syncthreads();
  const int e = tid & 127;
  const int chalf = tid >> 7;
  float acc[32];
#pragma unroll
  for (int c2 = 0; c2 < 32; ++c2) acc[c2] = 0.f;
  for (int j = 0; j < 64; ++j) {
    float vaj = va[j][e];
#pragma unroll
    for (int c2 = 0; c2 < 32; ++c2)
      acc[c2] += Ts[((chalf << 5) + c2) * 64 + j] * vaj;
  }
  const size_t ub = ((size_t)(((b << 2) + h) * HD) + (eh << 7) + e) * LL
                  + (nl << 6) + (chalf << 5);
#pragma unroll
  for (int c4 = 0; c4 < 8; ++c4) {
    u16x4 u;
    u.x = f2bfu(acc[(c4 << 2) + 0]); u.y = f2bfu(acc[(c4 << 2) + 1]);
    u.z = f2bfu(acc[(c4 << 2) + 2]); u.w = f2bfu(acc[(c4 << 2) + 3]);
    *(u16x4*)&Ut[ub + (c4 << 2)] = u;
  }
}

// ---- o = q*Sd + (c<=b)*Ai*u(from Ut), RMSNorm*g ; in-place over q ----
template <typename ST>
__global__ __launch_bounds__(256)
void o_kernel(ST* __restrict__ q, const float* __restrict__ Sdp,
              const unsigned short* __restrict__ Ut, const float* __restrict__ Ai,
              const float* __restrict__ g) {
  const int row = blockIdx.x;
  const int b = row >> 12;
  const int l = row & (LL - 1);
  const int n = l >> 6, c = l & 63;
  const int ch = threadIdx.x << 2;
  const size_t ro = (size_t)row * HID;
  float4 qv = ld4(&q[ro + ch]);
  float4 sd = *(const float4*)&Sdp[(size_t)((n << 2) + b) * HID + ch];
  float ox = qv.x*sd.x, oy = qv.y*sd.y, oz = qv.z*sd.z, ow = qv.w*sd.w;
  if (c <= b) {
    int bn = (b << 6) + n;
    float a = Ai[(bn << 2) + c];
    const int h = ch >> 8, e = ch & 255;
    const size_t ub = ((size_t)(((b << 2) + h) * HD) + e) * LL + (n << 6) + c;
    ox += a * bfu2f(Ut[ub + 0 * LL]);
    oy += a * bfu2f(Ut[ub + 1 * LL]);
    oz += a * bfu2f(Ut[ub + 2 * LL]);
    ow += a * bfu2f(Ut[ub + 3 * LL]);
  }
  float ss = ox*ox + oy*oy + oz*oz + ow*ow;
#pragma unroll
  for (int off = 32; off; off >>= 1) ss += __shfl_xor(ss, off);
  float scale = 1.f / sqrtf(ss * (1.f / HD) + 1e-5f);
  float4 gv = *(const float4*)&g[ch & (HD - 1)];
  st4(&q[ro + ch], make_float4(ox*scale*gv.x, oy*scale*gv.y, oz*scale*gv.z, ow*scale*gv.w));
}

// ---- reduce partials -> Sout ----
__global__ __launch_bounds__(256)
void sreduce_kernel(const float* __restrict__ Spart, float* __restrict__ Sout,
                    int ngroups) {
  size_t i = ((size_t)blockIdx.x * 256 + threadIdx.x) << 2;
  float4 s = make_float4(0.f, 0.f, 0.f, 0.f);
  for (int g = 0; g < ngroups; ++g) {
    float4 p = *(const float4*)&Spart[(size_t)g * SSIZE + i];
    s.x += p.x; s.y += p.y; s.z += p.z; s.w += p.w;
  }
  *(float4*)&Sout[i] = s;
}

extern "C" void kernel_launch(void* const* d_in, const int* in_sizes, int n_in,
                              void* d_out, int out_size, void* d_ws, size_t ws_size,
                              hipStream_t stream) {
  const float* x  = (const float*)d_in[0];
  const float* Wq = (const float*)d_in[1];
  const float* Wk = (const float*)d_in[2];
  const float* Wv = (const float*)d_in[3];
  const float* Wb = (const float*)d_in[4];
  const float* cq = (const float*)d_in[5];
  const float* ck = (const float*)d_in[6];
  const float* cv = (const float*)d_in[7];
  const float* g  = (const float*)d_in[8];
  const float* Wo = (const float*)d_in[9];
  float* out  = (float*)d_out;
  float* Sout = out + (size_t)ROWS * HID;

  const size_t F = (size_t)ROWS * HID;
  char* w = (char*)d_ws;
  float* kbuf  = (float*)w;  w += F * 4;   // -> Spart after ucompute
  bf16*  xb    = (bf16*)w;   w += F * 2;   // -> kt after v-GEMM
  bf16*  qbuf  = (bf16*)w;   w += F * 2;   // xlo first, then q
  bf16*  vbuf  = (bf16*)w;   w += F * 2;
  unsigned short* Wqt  = (unsigned short*)w; w += (size_t)HID * HID * 2;
  unsigned short* Wvt  = (unsigned short*)w; w += (size_t)HID * HID * 2;
  unsigned short* Wot  = (unsigned short*)w; w += (size_t)HID * HID * 2;
  unsigned short* Wkht = (unsigned short*)w; w += (size_t)HID * HID * 2;
  unsigned short* Wklt = (unsigned short*)w; w += (size_t)HID * HID * 2;
  float* Tg    = (float*)w;  w += (size_t)BB * NCH * 4096 * 4;
  float* betab = (float*)w;  w += (size_t)ROWS * NH * 4;
  float* Aib   = (float*)w;  w += (size_t)BB * NCH * 4 * 4;
  float* Pb    = (float*)w;  w += (size_t)BB * NCH * HID * 4;
  float* Rb    = (float*)w;  w += (size_t)BB * NCH * HID * 4;
  float* Sdp   = (float*)w;  w += (size_t)BB * NCH * HID * 4;
  const size_t need = (size_t)(w - (char*)d_ws);
  if (ws_size < need) return;

  dim3 gg(ROWS / 128, HID / 128);
  float* linf = out;            // fp32 lin scratch (k path)
  bf16*  linb = (bf16*)out;     // bf16 lin scratch (q/v paths), later Ut
  bf16*  xlo  = qbuf;           // alias: dead once conv8<0> writes qbuf

  prep_kernel<<<ROWS / 4, 256, 0, stream>>>(x, Wb, xb, xlo, betab);
  convT_all<<<dim3(16, 16, 4), 256, 0, stream>>>(Wq, Wv, Wo, Wk, Wqt, Wvt, Wot,
                                                 Wkht, Wklt);

  // k first (uses xlo which aliases qbuf); fp32 lin
  mfma_gemm3<<<gg, 256, 0, stream>>>((const unsigned short*)xb,
                                     (const unsigned short*)xlo, Wkht, Wklt, linf);
  conv8_kernel<1, float, float><<<ROWS / 8, 256, 0, stream>>>(linf, ck, betab, kbuf);
  mfma_gemm<bf16><<<gg, 256, 0, stream>>>((const unsigned short*)xb, Wqt, linb);
  conv8_kernel<0, bf16, bf16><<<ROWS / 8, 256, 0, stream>>>(linb, cq, betab, qbuf);
  mfma_gemm<bf16><<<gg, 256, 0, stream>>>((const unsigned short*)xb, Wvt, linb);
  conv8_kernel<2, bf16, bf16><<<ROWS / 8, 256, 0, stream>>>(linb, cv, betab, vbuf);
  // lin region now free until ucompute/out-GEMM

  // xb now dead -> kt[ch][row] bf16
  unsigned short* kt = (unsigned short*)xb;
  ktrans_kernel<<<dim3(ROWS / 64, HID / 64), 256, 0, stream>>>(kbuf, kt);

  chunkT_kernel<<<BB * NCH, 256, 0, stream>>>(kbuf, betab, Tg);
  prct_kernel<bf16><<<BB * NCH * NH, 256, 0, stream>>>(kbuf, vbuf, betab, Tg, Pb, Rb);
  scan_kernel<<<16, 256, 0, stream>>>(Pb, Rb, Sdp);
  ai_kernel<bf16><<<BB * NCH, 256, 0, stream>>>(qbuf, kbuf, Aib);

  // Ut (bf16, 32MB) in the free d_out scratch region
  unsigned short* Ut = (unsigned short*)linb;
  ucompute_kernel<<<BB * NCH * NH * 2, 256, 0, stream>>>(kbuf, vbuf, betab, Tg,
                                                         Sdp, Ut);
  o_kernel<bf16><<<ROWS, 256, 0, stream>>>(qbuf, Sdp, Ut, Aib, g);

  // kbuf now dead -> Spart (8 x 4MB fp32)
  float* Spart = kbuf;
  const int ngroups = 8;
  mfma_gemmS<<<dim3(2, 2, 16 * ngroups), 256, 0, stream>>>(kt, Ut, Spart, ngroups);
  sreduce_kernel<<<SSIZE / 1024, 256, 0, stream>>>(Spart, Sout, ngroups);

  // final output GEMM overwrites the Ut scratch region with out
  mfma_gemm<float><<<gg, 256, 0, stream>>>((const unsigned short*)qbuf, Wot, out);
}

// Round 15
// 678.745 us; speedup vs baseline: 1.2473x; 1.0401x over previous
//
#include <hip/hip_runtime.h>
#include <hip/hip_bf16.h>

#define HID 1024
#define NH 4
#define HD 256
#define NCH 64
#define BB 4
#define LL 4096
#define ROWS (BB*LL)
#define SSIZE (BB*NH*HD*HD)

typedef __hip_bfloat16 bf16;
typedef __attribute__((ext_vector_type(8))) short short8;
typedef __attribute__((ext_vector_type(4))) float f32x4;

struct u16x4 { unsigned short x, y, z, w; };

__device__ __forceinline__ float bfu2f(unsigned short u) {
  return __uint_as_float(((unsigned int)u) << 16);
}
__device__ __forceinline__ unsigned short f2bfu(float f) {
  unsigned int x = __float_as_uint(f);
  return (unsigned short)((x + 0x7FFFu + ((x >> 16) & 1u)) >> 16);
}
__device__ __forceinline__ float ldv(const float* p) { return *p; }
__device__ __forceinline__ float ldv(const bf16* p) { return bfu2f(*(const unsigned short*)p); }
__device__ __forceinline__ float4 ld4(const float* p) { return *(const float4*)p; }
__device__ __forceinline__ float4 ld4(const bf16* p) {
  u16x4 u = *(const u16x4*)p;
  return make_float4(bfu2f(u.x), bfu2f(u.y), bfu2f(u.z), bfu2f(u.w));
}
__device__ __forceinline__ void st4(float* p, float4 v) { *(float4*)p = v; }
__device__ __forceinline__ void st4(bf16* p, float4 v) {
  u16x4 u; u.x = f2bfu(v.x); u.y = f2bfu(v.y); u.z = f2bfu(v.z); u.w = f2bfu(v.w);
  *(u16x4*)p = u;
}
__device__ __forceinline__ void stc(float* C, size_t i, float v) { C[i] = v; }
__device__ __forceinline__ void stc(bf16* C, size_t i, float v) {
  ((unsigned short*)C)[i] = f2bfu(v);
}

typedef const __attribute__((address_space(1))) unsigned int* gptr_t;
typedef __attribute__((address_space(3))) unsigned int* lptr_t;
__device__ __forceinline__ void gload16(const void* g, void* l) {
  __builtin_amdgcn_global_load_lds((gptr_t)g, (lptr_t)l, 16, 0, 0);
}

// ================= device bodies =================

// ---- MFMA GEMM body: C[128x128 tile] = A @ Bt^T ----
template <typename OT>
__device__ __forceinline__
void gemm_body(const unsigned short* __restrict__ A,
               const unsigned short* __restrict__ Bt, OT* __restrict__ C,
               int m0, int n0, unsigned short* Asl, unsigned short* Bsl) {
  const int tid = threadIdx.x;
  const int wave = tid >> 6, lane = tid & 63;
  const int wr = wave >> 1, wc = wave & 1;
  f32x4 acc[4][4] = {};
  const int cA = (wave << 6) + lane;
  for (int k0 = 0; k0 < HID; k0 += 32) {
#pragma unroll
    for (int i = 0; i < 2; ++i) {
      int c = cA + (i << 8);
      int row = c >> 2, ko = (c & 3) << 3;
      gload16(&A[(size_t)(m0 + row) * HID + k0 + ko],
              &Asl[(size_t)((i << 8) + (wave << 6)) * 8]);
      gload16(&Bt[(size_t)(n0 + row) * HID + k0 + ko],
              &Bsl[(size_t)((i << 8) + (wave << 6)) * 8]);
    }
    __syncthreads();
    short8 af[4], bfr[4];
#pragma unroll
    for (int f = 0; f < 4; ++f) {
      int ra = (wr << 6) + (f << 4) + (lane & 15);
      af[f] = *(const short8*)&Asl[ra * 32 + ((lane >> 4) << 3)];
      int rb = (wc << 6) + (f << 4) + (lane & 15);
      bfr[f] = *(const short8*)&Bsl[rb * 32 + ((lane >> 4) << 3)];
    }
#pragma unroll
    for (int i = 0; i < 4; ++i)
#pragma unroll
      for (int j = 0; j < 4; ++j)
        acc[i][j] = __builtin_amdgcn_mfma_f32_16x16x32_bf16(af[i], bfr[j],
                                                            acc[i][j], 0, 0, 0);
    __syncthreads();
  }
#pragma unroll
  for (int i = 0; i < 4; ++i) {
    int r0 = m0 + (wr << 6) + (i << 4) + ((lane >> 4) << 2);
#pragma unroll
    for (int j = 0; j < 4; ++j) {
      int c0 = n0 + (wc << 6) + (j << 4) + (lane & 15);
#pragma unroll
      for (int r = 0; r < 4; ++r)
        stc(C, (size_t)(r0 + r) * HID + c0, acc[i][j][r]);
    }
  }
}

// ---- conv body: causal depthwise conv(K=4)+SiLU (+norm/+beta), 8 rows ----
template <int MODE, typename IT, typename ST>
__device__ __forceinline__
void conv8_body(const IT* __restrict__ lin, const float* __restrict__ w,
                const float* __restrict__ beta, ST* __restrict__ out, int row0) {
  const int tid = threadIdx.x;
  const int ch = tid << 2;
  const int h = tid >> 6;
  float wv[4][4];
#pragma unroll
  for (int j = 0; j < 4; ++j) {
    float4 t4 = *(const float4*)&w[(ch + j) << 2];
    wv[j][0] = t4.x; wv[j][1] = t4.y; wv[j][2] = t4.z; wv[j][3] = t4.w;
  }
  const int l0 = row0 & (LL - 1);
  const bool hasprev = (l0 != 0);
  float4 xw0, xw1, xw2, xw3;
  const float4 z4 = make_float4(0.f, 0.f, 0.f, 0.f);
  xw0 = hasprev ? ld4(&lin[(size_t)(row0 - 3) * HID + ch]) : z4;
  xw1 = hasprev ? ld4(&lin[(size_t)(row0 - 2) * HID + ch]) : z4;
  xw2 = hasprev ? ld4(&lin[(size_t)(row0 - 1) * HID + ch]) : z4;
#pragma unroll
  for (int r = 0; r < 8; ++r) {
    const int gr = row0 + r;
    xw3 = ld4(&lin[(size_t)gr * HID + ch]);
    float y[4];
#pragma unroll
    for (int j = 0; j < 4; ++j) {
      float xv0 = j == 0 ? xw0.x : j == 1 ? xw0.y : j == 2 ? xw0.z : xw0.w;
      float xv1 = j == 0 ? xw1.x : j == 1 ? xw1.y : j == 2 ? xw1.z : xw1.w;
      float xv2 = j == 0 ? xw2.x : j == 1 ? xw2.y : j == 2 ? xw2.z : xw2.w;
      float xv3 = j == 0 ? xw3.x : j == 1 ? xw3.y : j == 2 ? xw3.z : xw3.w;
      y[j] = xv0 * wv[j][0] + xv1 * wv[j][1] + xv2 * wv[j][2] + xv3 * wv[j][3];
      y[j] = y[j] / (1.f + expf(-y[j]));
    }
    float scale;
    if (MODE < 2) {
      float ss = y[0]*y[0] + y[1]*y[1] + y[2]*y[2] + y[3]*y[3];
#pragma unroll
      for (int off = 32; off; off >>= 1) ss += __shfl_xor(ss, off);  // wave = head
      scale = 1.f / sqrtf(ss);
    } else {
      scale = beta[(gr << 2) + h];
    }
    st4(&out[(size_t)gr * HID + ch],
        make_float4(y[0]*scale, y[1]*scale, y[2]*scale, y[3]*scale));
    xw0 = xw1; xw1 = xw2; xw2 = xw3;
  }
}

// ================= fused kernels =================

// ---- prep (bx<4096) + weight conversions (bx>=4096) ----
__global__ __launch_bounds__(256)
void prep_convT(const float* __restrict__ x, const float* __restrict__ Wb,
                const float* __restrict__ Wq, const float* __restrict__ Wv,
                const float* __restrict__ Wo, const float* __restrict__ Wk,
                bf16* __restrict__ hi, bf16* __restrict__ lo,
                float* __restrict__ beta,
                unsigned short* __restrict__ Wqt, unsigned short* __restrict__ Wvt,
                unsigned short* __restrict__ Wot, unsigned short* __restrict__ Wkht,
                unsigned short* __restrict__ Wklt) {
  __shared__ float t[64][65];
  const int bx = blockIdx.x;
  const int tid = threadIdx.x;
  if (bx < 4096) {
    const int wave = tid >> 6, lane = tid & 63;
    const int m = (bx << 2) + wave;
    float a0 = 0.f, a1 = 0.f, a2 = 0.f, a3 = 0.f;
#pragma unroll
    for (int it = 0; it < 4; ++it) {
      int f4 = (it << 6) + lane;
      size_t e = (size_t)m * 256 + f4;
      float4 v = *(const float4*)&x[e << 2];
      u16x4 h; h.x = f2bfu(v.x); h.y = f2bfu(v.y); h.z = f2bfu(v.z); h.w = f2bfu(v.w);
      *(u16x4*)&hi[e << 2] = h;
      u16x4 l;
      l.x = f2bfu(v.x - bfu2f(h.x)); l.y = f2bfu(v.y - bfu2f(h.y));
      l.z = f2bfu(v.z - bfu2f(h.z)); l.w = f2bfu(v.w - bfu2f(h.w));
      *(u16x4*)&lo[e << 2] = l;
      const float xs[4] = {v.x, v.y, v.z, v.w};
#pragma unroll
      for (int j = 0; j < 4; ++j) {
        float4 wb = *(const float4*)&Wb[((f4 << 2) + j) << 2];
        a0 += xs[j] * wb.x; a1 += xs[j] * wb.y;
        a2 += xs[j] * wb.z; a3 += xs[j] * wb.w;
      }
    }
#pragma unroll
    for (int off = 32; off; off >>= 1) {
      a0 += __shfl_xor(a0, off); a1 += __shfl_xor(a1, off);
      a2 += __shfl_xor(a2, off); a3 += __shfl_xor(a3, off);
    }
    if (lane == 0) {
      float4 r;
      r.x = 1.f / (1.f + expf(-a0)); r.y = 1.f / (1.f + expf(-a1));
      r.z = 1.f / (1.f + expf(-a2)); r.w = 1.f / (1.f + expf(-a3));
      *(float4*)&beta[m << 2] = r;
    }
  } else {
    const int idx = bx - 4096;              // 0..1023
    const int z = idx >> 8;                 // 0..3
    const int xy = idx & 255;
    const int kt = (xy & 15) << 6, nt = (xy >> 4) << 6;
    const float* W = z == 0 ? Wq : z == 1 ? Wv : z == 2 ? Wo : Wk;
#pragma unroll
    for (int i = 0; i < 16; ++i) {
      int id2 = tid + (i << 8);
      int r = id2 >> 6, c = id2 & 63;
      t[r][c] = W[(size_t)(kt + r) * HID + nt + c];
    }
    __syncthreads();
    if (z < 3) {
      unsigned short* Wt = z == 0 ? Wqt : z == 1 ? Wvt : Wot;
#pragma unroll
      for (int i = 0; i < 16; ++i) {
        int id2 = tid + (i << 8);
        int n = id2 >> 6, kk = id2 & 63;
        Wt[(size_t)(nt + n) * HID + kt + kk] = f2bfu(t[kk][n]);
      }
    } else {
#pragma unroll
      for (int i = 0; i < 16; ++i) {
        int id2 = tid + (i << 8);
        int n = id2 >> 6, kk = id2 & 63;
        float v = t[kk][n];
        unsigned short h = f2bfu(v);
        Wkht[(size_t)(nt + n) * HID + kt + kk] = h;
        Wklt[(size_t)(nt + n) * HID + kt + kk] = f2bfu(v - bfu2f(h));
      }
    }
  }
}

// ---- split-bf16 MFMA GEMM (k path) ----
__global__ __launch_bounds__(256)
void mfma_gemm3(const unsigned short* __restrict__ Ah_,
                const unsigned short* __restrict__ Al_,
                const unsigned short* __restrict__ Bh_,
                const unsigned short* __restrict__ Bl_,
                float* __restrict__ C) {
  __shared__ unsigned short Ah[128 * 32];
  __shared__ unsigned short Al[128 * 32];
  __shared__ unsigned short Bh[128 * 32];
  __shared__ unsigned short Bl[128 * 32];
  const int tid = threadIdx.x;
  const int wave = tid >> 6, lane = tid & 63;
  const int m0 = blockIdx.x << 7, n0 = blockIdx.y << 7;
  const int wr = wave >> 1, wc = wave & 1;
  f32x4 acc[4][4] = {};
  const int cA = (wave << 6) + lane;
  for (int k0 = 0; k0 < HID; k0 += 32) {
#pragma unroll
    for (int i = 0; i < 2; ++i) {
      int c = cA + (i << 8);
      int row = c >> 2, ko = (c & 3) << 3;
      size_t ga = (size_t)(m0 + row) * HID + k0 + ko;
      size_t gb = (size_t)(n0 + row) * HID + k0 + ko;
      size_t ldst = (size_t)((i << 8) + (wave << 6)) * 8;
      gload16(&Ah_[ga], &Ah[ldst]);
      gload16(&Al_[ga], &Al[ldst]);
      gload16(&Bh_[gb], &Bh[ldst]);
      gload16(&Bl_[gb], &Bl[ldst]);
    }
    __syncthreads();
    short8 ah[4], al[4], bh[4], bl[4];
#pragma unroll
    for (int f = 0; f < 4; ++f) {
      int ra = ((wr << 6) + (f << 4) + (lane & 15)) * 32 + ((lane >> 4) << 3);
      ah[f] = *(const short8*)&Ah[ra];
      al[f] = *(const short8*)&Al[ra];
      int rb = ((wc << 6) + (f << 4) + (lane & 15)) * 32 + ((lane >> 4) << 3);
      bh[f] = *(const short8*)&Bh[rb];
      bl[f] = *(const short8*)&Bl[rb];
    }
#pragma unroll
    for (int i = 0; i < 4; ++i)
#pragma unroll
      for (int j = 0; j < 4; ++j) {
        f32x4 a = acc[i][j];
        a = __builtin_amdgcn_mfma_f32_16x16x32_bf16(al[i], bh[j], a, 0, 0, 0);
        a = __builtin_amdgcn_mfma_f32_16x16x32_bf16(ah[i], bl[j], a, 0, 0, 0);
        a = __builtin_amdgcn_mfma_f32_16x16x32_bf16(ah[i], bh[j], a, 0, 0, 0);
        acc[i][j] = a;
      }
    __syncthreads();
  }
#pragma unroll
  for (int i = 0; i < 4; ++i) {
    int r0 = m0 + (wr << 6) + (i << 4) + ((lane >> 4) << 2);
#pragma unroll
    for (int j = 0; j < 4; ++j) {
      int c0 = n0 + (wc << 6) + (j << 4) + (lane & 15);
#pragma unroll
      for (int r = 0; r < 4; ++r)
        C[(size_t)(r0 + r) * HID + c0] = acc[i][j][r];
    }
  }
}

// ---- conv8 k (standalone, fp32->fp32) ----
__global__ __launch_bounds__(256)
void conv8_k(const float* __restrict__ lin, const float* __restrict__ w,
             const float* __restrict__ beta, float* __restrict__ out) {
  conv8_body<1, float, float>(lin, w, beta, out, blockIdx.x << 3);
}

// ---- q-GEMM and v-GEMM in one launch (z-select) ----
__global__ __launch_bounds__(256)
void qv_gemm(const unsigned short* __restrict__ A,
             const unsigned short* __restrict__ Wqt,
             const unsigned short* __restrict__ Wvt,
             bf16* __restrict__ linq, bf16* __restrict__ linv) {
  __shared__ unsigned short Asl[128 * 32];
  __shared__ unsigned short Bsl[128 * 32];
  const unsigned short* Bt = blockIdx.z ? Wvt : Wqt;
  bf16* C = blockIdx.z ? linv : linq;
  gemm_body<bf16>(A, Bt, C, blockIdx.x << 7, blockIdx.y << 7, Asl, Bsl);
}

// ---- conv q (bx<2048) + conv v (bx<4096) + ktrans (bx>=4096) ----
__global__ __launch_bounds__(256)
void convqv_ktrans(const bf16* __restrict__ linq, const bf16* __restrict__ linv,
                   const float* __restrict__ cq, const float* __restrict__ cv,
                   const float* __restrict__ beta, bf16* __restrict__ qbuf,
                   bf16* __restrict__ vbuf, const float* __restrict__ k,
                   unsigned short* __restrict__ kt) {
  __shared__ float t[64][65];
  const int bx = blockIdx.x;
  if (bx < 2048) {
    conv8_body<0, bf16, bf16>(linq, cq, beta, qbuf, bx << 3);
  } else if (bx < 4096) {
    conv8_body<2, bf16, bf16>(linv, cv, beta, vbuf, (bx - 2048) << 3);
  } else {
    const int idx = bx - 4096;                // 0..4095
    const int r0 = (idx & 255) << 6, c0 = (idx >> 8) << 6;
    const int tid = threadIdx.x;
#pragma unroll
    for (int i = 0; i < 16; ++i) {
      int id2 = tid + (i << 8);
      int rr = id2 >> 6, cc = id2 & 63;
      t[rr][cc] = k[(size_t)(r0 + rr) * HID + c0 + cc];
    }
    __syncthreads();
#pragma unroll
    for (int i = 0; i < 16; ++i) {
      int id2 = tid + (i << 8);
      int cc = id2 >> 6, rr = id2 & 63;
      kt[(size_t)(c0 + cc) * ROWS + r0 + rr] = f2bfu(t[rr][cc]);
    }
  }
}

// ---- per-(b,n): T recurrence (fp32), store T ----
__global__ __launch_bounds__(256)
void chunkT_kernel(const float* __restrict__ k, const float* __restrict__ beta,
                   float* __restrict__ Tg) {
  __shared__ float T[64][68];
  __shared__ float S1[64][68];
  __shared__ float S2[64][68];
  __shared__ float row_s[64];
  const int bn = blockIdx.x;
  const size_t base = (size_t)bn * 64 * HID;
  const int tid = threadIdx.x;
  const int tr = tid >> 4, tc = tid & 15;
  float acc[4][4] = {{0.f}};
  for (int d0 = 0; d0 < HID; d0 += 64) {
    const int h = d0 >> 8;
#pragma unroll
    for (int p = 0; p < 4; ++p) {
      int rr = (tid >> 4) + (p << 4);
      int c4 = (tid & 15) << 2;
      float4 a = *(const float4*)&k[base + (size_t)rr * HID + d0 + c4];
      float bta = beta[(((bn << 6) + rr) << 2) + h];
      S2[c4 + 0][rr] = a.x; S2[c4 + 1][rr] = a.y;
      S2[c4 + 2][rr] = a.z; S2[c4 + 3][rr] = a.w;
      S1[c4 + 0][rr] = a.x * bta; S1[c4 + 1][rr] = a.y * bta;
      S1[c4 + 2][rr] = a.z * bta; S1[c4 + 3][rr] = a.w * bta;
    }
    __syncthreads();
#pragma unroll
    for (int dd = 0; dd < 64; ++dd) {
      float4 a = *(const float4*)&S1[dd][tr << 2];
      float4 b = *(const float4*)&S2[dd][tc << 2];
      acc[0][0] += a.x*b.x; acc[0][1] += a.x*b.y; acc[0][2] += a.x*b.z; acc[0][3] += a.x*b.w;
      acc[1][0] += a.y*b.x; acc[1][1] += a.y*b.y; acc[1][2] += a.y*b.z; acc[1][3] += a.y*b.w;
      acc[2][0] += a.z*b.x; acc[2][1] += a.z*b.y; acc[2][2] += a.z*b.z; acc[2][3] += a.z*b.w;
      acc[3][0] += a.w*b.x; acc[3][1] += a.w*b.y; acc[3][2] += a.w*b.z; acc[3][3] += a.w*b.w;
    }
    __syncthreads();
  }
#pragma unroll
  for (int i = 0; i < 4; ++i)
#pragma unroll
    for (int j = 0; j < 4; ++j) {
      int ri = (tr << 2) + i, cj = (tc << 2) + j;
      T[ri][cj] = (ri == cj) ? 1.f : (ri > cj ? -acc[i][j] : 0.f);
    }
  __syncthreads();
  for (int i = 1; i < 64; ++i) {
    if (tid < 64) row_s[tid] = T[i][tid];
    __syncthreads();
    if (tid < 64) {
      float a = 0.f;
#pragma unroll 8
      for (int j = 0; j < 64; ++j) a += row_s[j] * T[j][tid];
      if (tid < i) T[i][tid] = row_s[tid] + a;
    }
    __syncthreads();
  }
#pragma unroll
  for (int ii = 0; ii < 4; ++ii) {
    int off = (tid << 4) + (ii << 2);
    int c = off >> 6, j = off & 63;
    *(float4*)&Tg[(size_t)bn * 4096 + off] = *(const float4*)&T[c][j];
  }
}

// ---- P,R via ct[j,ch] = sum_c T[c,j]*k[c,ch] ----
__global__ __launch_bounds__(256)
void prct_kernel(const float* __restrict__ k, const bf16* __restrict__ v,
                 const float* __restrict__ beta, const float* __restrict__ Tg,
                 float* __restrict__ P, float* __restrict__ R) {
  __shared__ float Ts[4096];
  __shared__ float bs[64];
  const int bn = blockIdx.x >> 2, h = blockIdx.x & 3;
  const int tid = threadIdx.x;
#pragma unroll
  for (int ii = 0; ii < 4; ++ii) {
    int off = (tid << 4) + (ii << 2);
    *(float4*)&Ts[off] = *(const float4*)&Tg[(size_t)bn * 4096 + off];
  }
  if (tid < 64) bs[tid] = beta[(((bn << 6) + tid) << 2) + h];
  __syncthreads();
  const int ch = (h << 8) + tid;
  const size_t base = (size_t)bn * 64 * HID;
  float ct[64];
#pragma unroll
  for (int j = 0; j < 64; ++j) ct[j] = 0.f;
  for (int c = 0; c < 64; ++c) {
    float kc = k[base + (size_t)c * HID + ch];
#pragma unroll
    for (int j = 0; j < 64; ++j) ct[j] += Ts[(c << 6) + j] * kc;
  }
  float p = 0.f, r = 0.f;
#pragma unroll
  for (int j = 0; j < 64; ++j) {
    float kj = k[base + (size_t)j * HID + ch];
    float vj = ldv(&v[base + (size_t)j * HID + ch]);
    p += bs[j] * kj * ct[j];
    r += vj * ct[j];
  }
  P[(size_t)bn * HID + ch] = p;
  R[(size_t)bn * HID + ch] = r;
}

// ---- scan (bx<16, prefetched) + Ai (bx>=16) ----
__global__ __launch_bounds__(256)
void scan_ai(const float* __restrict__ P, const float* __restrict__ R,
             float* __restrict__ Sdp, const bf16* __restrict__ q,
             const float* __restrict__ k, float* __restrict__ Ai) {
  const int bx = blockIdx.x;
  if (bx < 16) {
    const int b = bx >> 2;
    const int ch = ((bx & 3) << 8) + threadIdx.x;
    float S = 0.f;
    float p = P[(size_t)(b << 6) * HID + ch];
    float r = R[(size_t)(b << 6) * HID + ch];
    for (int n = 0; n < 64; ++n) {
      Sdp[(size_t)((n << 2) + b) * HID + ch] = S;
      float pn = 0.f, rn = 0.f;
      if (n < 63) {
        pn = P[(size_t)((b << 6) + n + 1) * HID + ch];
        rn = R[(size_t)((b << 6) + n + 1) * HID + ch];
      }
      S = S * (1.f - p) + r;
      p = pn; r = rn;
    }
  } else {
    const int bn = bx - 16;
    const int b = bn >> 6;
    const int wave = threadIdx.x >> 6, lane = threadIdx.x & 63;
    const size_t roff = ((size_t)bn * 64 + wave) * HID;
    float s = 0.f;
#pragma unroll
    for (int it = 0; it < 4; ++it) {
      int d = (lane << 2) + (it << 8);
      float4 a = ld4(&q[roff + d]);
      float4 b4 = *(const float4*)&k[roff + d];
      s += a.x*b4.x + a.y*b4.y + a.z*b4.z + a.w*b4.w;
    }
#pragma unroll
    for (int off = 32; off; off >>= 1) s += __shfl_xor(s, off);
    if (lane == 0) Ai[(bn << 2) + wave] = (wave <= b) ? s : 0.f;
  }
}

// ---- ucompute: u = T@(v - beta*k*Sd) in fp32, write Ut[bh*256+e][row] bf16 ----
__global__ __launch_bounds__(256)
void ucompute_kernel(const float* __restrict__ k, const bf16* __restrict__ v,
                     const float* __restrict__ beta, const float* __restrict__ Tg,
                     const float* __restrict__ Sdp, unsigned short* __restrict__ Ut) {
  __shared__ float Ts[4096];
  __shared__ float va[64][132];
  __shared__ float bs[64];
  const int bn = blockIdx.x >> 3;
  const int rr2 = blockIdx.x & 7;
  const int h = rr2 >> 1, eh = rr2 & 1;
  const int b = bn >> 6, nl = bn & 63;
  const int tid = threadIdx.x;
#pragma unroll
  for (int ii = 0; ii < 4; ++ii) {
    int off = (tid << 4) + (ii << 2);
    *(float4*)&Ts[off] = *(const float4*)&Tg[(size_t)bn * 4096 + off];
  }
  if (tid < 64) bs[tid] = beta[(((bn << 6) + tid) << 2) + h];
  __syncthreads();
  const size_t base = (size_t)bn * 64 * HID;
  const int ch0 = (h << 8) + (eh << 7);
#pragma unroll
  for (int p = 0; p < 8; ++p) {
    int idx = tid + (p << 8);
    int row = idx >> 5;
    int col4 = (idx & 31) << 2;
    int chg = ch0 + col4;
    float4 sd4 = *(const float4*)&Sdp[(size_t)((nl << 2) + b) * HID + chg];
    float4 k4 = *(const float4*)&k[base + (size_t)row * HID + chg];
    float4 v4 = ld4(&v[base + (size_t)row * HID + chg]);
    float bt = bs[row];
    va[row][col4 + 0] = v4.x - bt * k4.x * sd4.x;
    va[row][col4 + 1] = v4.y - bt * k4.y * sd4.y;
    va[row][col4 + 2] = v4.z - bt * k4.z * sd4.z;
    va[row][col4 + 3] = v4.w - bt * k4.w * sd4.w;
  }
  __syncthreads();
  const int e = tid & 127;
  const int chalf = tid >> 7;
  float acc[32];
#pragma unroll
  for (int c2 = 0; c2 < 32; ++c2) acc[c2] = 0.f;
  for (int j = 0; j < 64; ++j) {
    float vaj = va[j][e];
#pragma unroll
    for (int c2 = 0; c2 < 32; ++c2)
      acc[c2] += Ts[((chalf << 5) + c2) * 64 + j] * vaj;
  }
  const size_t ub = ((size_t)(((b << 2) + h) * HD) + (eh << 7) + e) * LL
                  + (nl << 6) + (chalf << 5);
#pragma unroll
  for (int c4 = 0; c4 < 8; ++c4) {
    u16x4 u;
    u.x = f2bfu(acc[(c4 << 2) + 0]); u.y = f2bfu(acc[(c4 << 2) + 1]);
    u.z = f2bfu(acc[(c4 << 2) + 2]); u.w = f2bfu(acc[(c4 << 2) + 3]);
    *(u16x4*)&Ut[ub + (c4 << 2)] = u;
  }
}

// ---- o = q*Sd + (c<=b)*Ai*u(from Ut), RMSNorm*g ; in-place over q ----
__global__ __launch_bounds__(256)
void o_kernel(bf16* __restrict__ q, const float* __restrict__ Sdp,
              const unsigned short* __restrict__ Ut, const float* __restrict__ Ai,
              const float* __restrict__ g) {
  const int row = blockIdx.x;
  const int b = row >> 12;
  const int l = row & (LL - 1);
  const int n = l >> 6, c = l & 63;
  const int ch = threadIdx.x << 2;
  const size_t ro = (size_t)row * HID;
  float4 qv = ld4(&q[ro + ch]);
  float4 sd = *(const float4*)&Sdp[(size_t)((n << 2) + b) * HID + ch];
  float ox = qv.x*sd.x, oy = qv.y*sd.y, oz = qv.z*sd.z, ow = qv.w*sd.w;
  if (c <= b) {
    int bn = (b << 6) + n;
    float a = Ai[(bn << 2) + c];
    const int h = ch >> 8, e = ch & 255;
    const size_t ub = ((size_t)(((b << 2) + h) * HD) + e) * LL + (n << 6) + c;
    ox += a * bfu2f(Ut[ub + 0 * LL]);
    oy += a * bfu2f(Ut[ub + 1 * LL]);
    oz += a * bfu2f(Ut[ub + 2 * LL]);
    ow += a * bfu2f(Ut[ub + 3 * LL]);
  }
  float ss = ox*ox + oy*oy + oz*oz + ow*ow;
#pragma unroll
  for (int off = 32; off; off >>= 1) ss += __shfl_xor(ss, off);
  float scale = 1.f / sqrtf(ss * (1.f / HD) + 1e-5f);
  float4 gv = *(const float4*)&g[ch & (HD - 1)];
  st4(&q[ro + ch], make_float4(ox*scale*gv.x, oy*scale*gv.y, oz*scale*gv.z, ow*scale*gv.w));
}

// ---- MFMA GEMM for S partials ----
__global__ __launch_bounds__(256)
void mfma_gemmS(const unsigned short* __restrict__ At,
                const unsigned short* __restrict__ Bt,
                float* __restrict__ Spart, int ngroups) {
  __shared__ unsigned short Asl[128 * 32];
  __shared__ unsigned short Bsl[128 * 32];
  const int tid = threadIdx.x;
  const int wave = tid >> 6, lane = tid & 63;
  const int m0 = blockIdx.x << 7, n0 = blockIdx.y << 7;
  const int bh = blockIdx.z / ngroups;
  const int ng = blockIdx.z % ngroups;
  const int b = bh >> 2, h = bh & 3;
  const size_t kbase = (size_t)b * LL + (size_t)ng * (LL / ngroups);
  const int wr = wave >> 1, wc = wave & 1;
  f32x4 acc[4][4] = {};
  const int cA = (wave << 6) + lane;
  for (int k0 = 0; k0 < LL / ngroups; k0 += 32) {
#pragma unroll
    for (int i = 0; i < 2; ++i) {
      int c = cA + (i << 8);
      int row = c >> 2, ko = (c & 3) << 3;
      gload16(&At[((size_t)(h * HD + m0 + row)) * ROWS + kbase + k0 + ko],
              &Asl[(size_t)((i << 8) + (wave << 6)) * 8]);
      gload16(&Bt[((size_t)(bh * HD + n0 + row)) * LL + (size_t)ng * (LL / ngroups) + k0 + ko],
              &Bsl[(size_t)((i << 8) + (wave << 6)) * 8]);
    }
    __syncthreads();
    short8 af[4], bfr[4];
#pragma unroll
    for (int f = 0; f < 4; ++f) {
      int ra = (wr << 6) + (f << 4) + (lane & 15);
      af[f] = *(const short8*)&Asl[ra * 32 + ((lane >> 4) << 3)];
      int rb = (wc << 6) + (f << 4) + (lane & 15);
      bfr[f] = *(const short8*)&Bsl[rb * 32 + ((lane >> 4) << 3)];
    }
#pragma unroll
    for (int i = 0; i < 4; ++i)
#pragma unroll
      for (int j = 0; j < 4; ++j)
        acc[i][j] = __builtin_amdgcn_mfma_f32_16x16x32_bf16(af[i], bfr[j],
                                                            acc[i][j], 0, 0, 0);
    __syncthreads();
  }
  float* Cp = Spart + (size_t)ng * SSIZE + (size_t)bh * HD * HD;
#pragma unroll
  for (int i = 0; i < 4; ++i) {
    int r0 = m0 + (wr << 6) + (i << 4) + ((lane >> 4) << 2);
#pragma unroll
    for (int j = 0; j < 4; ++j) {
      int c0 = n0 + (wc << 6) + (j << 4) + (lane & 15);
#pragma unroll
      for (int r = 0; r < 4; ++r)
        Cp[(size_t)(r0 + r) * HD + c0] = acc[i][j][r];
    }
  }
}

// ---- out-GEMM (bx<1024) + sreduce (bx>=1024) ----
__global__ __launch_bounds__(256)
void out_sreduce(const unsigned short* __restrict__ A,
                 const unsigned short* __restrict__ Bt, float* __restrict__ C,
                 const float* __restrict__ Spart, float* __restrict__ Sout,
                 int ngroups) {
  __shared__ unsigned short Asl[128 * 32];
  __shared__ unsigned short Bsl[128 * 32];
  const int bx = blockIdx.x;
  if (bx < 1024) {
    gemm_body<float>(A, Bt, C, (bx >> 3) << 7, (bx & 7) << 7, Asl, Bsl);
  } else {
    size_t i = ((size_t)(bx - 1024) * 256 + threadIdx.x) << 2;
    float4 s = make_float4(0.f, 0.f, 0.f, 0.f);
    for (int g = 0; g < ngroups; ++g) {
      float4 p = *(const float4*)&Spart[(size_t)g * SSIZE + i];
      s.x += p.x; s.y += p.y; s.z += p.z; s.w += p.w;
    }
    *(float4*)&Sout[i] = s;
  }
}

extern "C" void kernel_launch(void* const* d_in, const int* in_sizes, int n_in,
                              void* d_out, int out_size, void* d_ws, size_t ws_size,
                              hipStream_t stream) {
  const float* x  = (const float*)d_in[0];
  const float* Wq = (const float*)d_in[1];
  const float* Wk = (const float*)d_in[2];
  const float* Wv = (const float*)d_in[3];
  const float* Wb = (const float*)d_in[4];
  const float* cq = (const float*)d_in[5];
  const float* ck = (const float*)d_in[6];
  const float* cv = (const float*)d_in[7];
  const float* g  = (const float*)d_in[8];
  const float* Wo = (const float*)d_in[9];
  float* out  = (float*)d_out;
  float* Sout = out + (size_t)ROWS * HID;

  const size_t F = (size_t)ROWS * HID;
  char* w = (char*)d_ws;
  float* kbuf  = (float*)w;  w += F * 4;   // -> Spart after ucompute
  bf16*  xb    = (bf16*)w;   w += F * 2;   // -> kt after qv GEMMs
  bf16*  qbuf  = (bf16*)w;   w += F * 2;   // xlo first, then q
  bf16*  vbuf  = (bf16*)w;   w += F * 2;
  unsigned short* Wqt  = (unsigned short*)w; w += (size_t)HID * HID * 2;
  unsigned short* Wvt  = (unsigned short*)w; w += (size_t)HID * HID * 2;
  unsigned short* Wot  = (unsigned short*)w; w += (size_t)HID * HID * 2;
  unsigned short* Wkht = (unsigned short*)w; w += (size_t)HID * HID * 2;
  unsigned short* Wklt = (unsigned short*)w; w += (size_t)HID * HID * 2;
  float* Tg    = (float*)w;  w += (size_t)BB * NCH * 4096 * 4;
  float* betab = (float*)w;  w += (size_t)ROWS * NH * 4;
  float* Aib   = (float*)w;  w += (size_t)BB * NCH * 4 * 4;
  float* Pb    = (float*)w;  w += (size_t)BB * NCH * HID * 4;
  float* Rb    = (float*)w;  w += (size_t)BB * NCH * HID * 4;
  float* Sdp   = (float*)w;  w += (size_t)BB * NCH * HID * 4;
  const size_t need = (size_t)(w - (char*)d_ws);
  if (ws_size < need) return;

  dim3 gg(ROWS / 128, HID / 128);
  float* linf = out;                    // fp32 lin scratch (k path)
  bf16*  linq = (bf16*)out;             // bf16 lin q (first 32MB of d_out)
  bf16*  linv = linq + F;               // bf16 lin v (second 32MB)
  bf16*  xlo  = qbuf;                   // alias: dead once conv q writes qbuf

  // 1: prep + weight conversions
  prep_convT<<<4096 + 1024, 256, 0, stream>>>(x, Wb, Wq, Wv, Wo, Wk, xb, xlo,
                                              betab, Wqt, Wvt, Wot, Wkht, Wklt);
  // 2: k GEMM (split bf16; uses xlo aliasing qbuf)
  mfma_gemm3<<<gg, 256, 0, stream>>>((const unsigned short*)xb,
                                     (const unsigned short*)xlo, Wkht, Wklt, linf);
  // 3: conv k
  conv8_k<<<ROWS / 8, 256, 0, stream>>>(linf, ck, betab, kbuf);
  // 4: q + v GEMMs (one launch)
  qv_gemm<<<dim3(ROWS / 128, HID / 128, 2), 256, 0, stream>>>(
      (const unsigned short*)xb, Wqt, Wvt, linq, linv);
  // 5: conv q + conv v + ktrans (xb dead -> kt)
  unsigned short* kt = (unsigned short*)xb;
  convqv_ktrans<<<2048 + 2048 + 4096, 256, 0, stream>>>(linq, linv, cq, cv,
                                                        betab, qbuf, vbuf,
                                                        kbuf, kt);
  // 6: T recurrence
  chunkT_kernel<<<BB * NCH, 256, 0, stream>>>(kbuf, betab, Tg);
  // 7: P,R
  prct_kernel<<<BB * NCH * NH, 256, 0, stream>>>(kbuf, vbuf, betab, Tg, Pb, Rb);
  // 8: scan + Ai
  scan_ai<<<16 + BB * NCH, 256, 0, stream>>>(Pb, Rb, Sdp, qbuf, kbuf, Aib);
  // 9: Ut (bf16, 32MB) into the free d_out scratch region
  unsigned short* Ut = (unsigned short*)out;
  ucompute_kernel<<<BB * NCH * NH * 2, 256, 0, stream>>>(kbuf, vbuf, betab, Tg,
                                                         Sdp, Ut);
  // 10: o (in-place over qbuf)
  o_kernel<<<ROWS, 256, 0, stream>>>(qbuf, Sdp, Ut, Aib, g);
  // 11: S partial GEMMs (kbuf dead -> Spart)
  float* Spart = kbuf;
  const int ngroups = 8;
  mfma_gemmS<<<dim3(2, 2, 16 * ngroups), 256, 0, stream>>>(kt, Ut, Spart, ngroups);
  // 12: out-GEMM (overwrites Ut scratch) + S reduce
  out_sreduce<<<1024 + SSIZE / 1024, 256, 0, stream>>>(
      (const unsigned short*)qbuf, Wot, out, Spart, Sout, ngroups);
}